// Round 1
// baseline (518.874 us; speedup 1.0000x reference)
//
#include <hip/hip_runtime.h>
#include <math.h>

#define QPW 8   // queries per wave
#define WPB 4   // waves per block (block = 256)

__device__ __forceinline__ float wave_reduce_sum(float v) {
    #pragma unroll
    for (int off = 32; off >= 1; off >>= 1)
        v += __shfl_xor(v, off, 64);
    return v;
}

__global__ __launch_bounds__(256)
void knn_loss_kernel(const float* __restrict__ coord_q,
                     const float* __restrict__ feat_q,
                     int Nq,
                     const float* __restrict__ coord_d,
                     const float* __restrict__ feat_d,
                     int Nd,
                     float scale,
                     float* __restrict__ out)
{
    const int lane = threadIdx.x & 63;
    const int wave = (threadIdx.x >> 6) + blockIdx.x * WPB;
    int qbase = wave * QPW;
    if (qbase >= Nq) return;
    // force wave-uniform so query coords can scalarize
    qbase = __builtin_amdgcn_readfirstlane(qbase);

    // wave-uniform query coords
    float qx[QPW], qy[QPW], qz[QPW];
    #pragma unroll
    for (int q = 0; q < QPW; ++q) {
        qx[q] = coord_q[(qbase + q) * 3 + 0];
        qy[q] = coord_q[(qbase + q) * 3 + 1];
        qz[q] = coord_q[(qbase + q) * 3 + 2];
    }

    const float INF = 3.0e38f;
    // per-lane sorted top-4 (ascending); all indices compile-time after unroll
    float bd[QPW][4];
    int   bi[QPW][4];
    #pragma unroll
    for (int q = 0; q < QPW; ++q) {
        #pragma unroll
        for (int k = 0; k < 4; ++k) { bd[q][k] = INF; bi[q][k] = 0x7fffffff; }
    }

    // scan database: lane-strided, each loaded point tested vs 8 queries
    for (int base = 0; base < Nd; base += 64) {
        const int p = base + lane;
        float px = 0.f, py = 0.f, pz = 0.f;
        const bool valid = (p < Nd);
        if (valid) {
            px = coord_d[p * 3 + 0];
            py = coord_d[p * 3 + 1];
            pz = coord_d[p * 3 + 2];
        }
        #pragma unroll
        for (int q = 0; q < QPW; ++q) {
            float dx = px - qx[q], dy = py - qy[q], dz = pz - qz[q];
            float d2 = dx * dx + dy * dy + dz * dz;
            if (!valid) d2 = INF;
            if (d2 < bd[q][3]) {
                if (d2 < bd[q][2]) {
                    bd[q][3] = bd[q][2]; bi[q][3] = bi[q][2];
                    if (d2 < bd[q][1]) {
                        bd[q][2] = bd[q][1]; bi[q][2] = bi[q][1];
                        if (d2 < bd[q][0]) {
                            bd[q][1] = bd[q][0]; bi[q][1] = bi[q][0];
                            bd[q][0] = d2; bi[q][0] = p;
                        } else { bd[q][1] = d2; bi[q][1] = p; }
                    } else { bd[q][2] = d2; bi[q][2] = p; }
                } else { bd[q][3] = d2; bi[q][3] = p; }
            }
        }
    }

    float wave_acc = 0.0f;

    #pragma unroll
    for (int q = 0; q < QPW; ++q) {
        // wave-wide merge: 4 rounds of lexicographic (d2, idx) min over lane heads
        int ni_[4];
        #pragma unroll
        for (int k = 0; k < 4; ++k) {
            float cd = bd[q][0];
            int   ci = bi[q][0];
            #pragma unroll
            for (int off = 32; off >= 1; off >>= 1) {
                float od = __shfl_xor(cd, off, 64);
                int   oi = __shfl_xor(ci, off, 64);
                if (od < cd || (od == cd && oi < ci)) { cd = od; ci = oi; }
            }
            ni_[k] = ci;
            if (bi[q][0] == ci) { // winning lane pops its head (static shifts)
                bd[q][0] = bd[q][1]; bi[q][0] = bi[q][1];
                bd[q][1] = bd[q][2]; bi[q][1] = bi[q][2];
                bd[q][2] = bd[q][3]; bi[q][2] = bi[q][3];
                bd[q][3] = INF;      bi[q][3] = 0x7fffffff;
            }
        }

        // cosine sims with fused normalization: 96 dims = lane + (64+lane for lane<32)
        const float* fq = feat_q + (size_t)(qbase + q) * 96;
        const float  qf0 = fq[lane];
        const float  qf1 = (lane < 32) ? fq[64 + lane] : 0.0f;
        const float  ssq = wave_reduce_sum(qf0 * qf0 + qf1 * qf1);

        float sim[4];
        #pragma unroll
        for (int k = 0; k < 4; ++k) {
            const float* fd = feat_d + (size_t)ni_[k] * 96;
            const float df0 = fd[lane];
            const float df1 = (lane < 32) ? fd[64 + lane] : 0.0f;
            const float dot = wave_reduce_sum(qf0 * df0 + qf1 * df1);
            const float ssd = wave_reduce_sum(df0 * df0 + df1 * df1);
            // 1/(max(|fq|,1e-12)*max(|fd|,1e-12)); norms ~9.8 so clamp moot
            const float inv = rsqrtf(fmaxf(ssq, 1e-24f) * fmaxf(ssd, 1e-24f));
            sim[k] = dot * inv * 10.0f; // / TEMP
        }

        // softmax over 4, then -log(sum p^2 + eps)
        const float m = fmaxf(fmaxf(sim[0], sim[1]), fmaxf(sim[2], sim[3]));
        const float e0 = __expf(sim[0] - m);
        const float e1 = __expf(sim[1] - m);
        const float e2 = __expf(sim[2] - m);
        const float e3 = __expf(sim[3] - m);
        const float s  = e0 + e1 + e2 + e3;
        const float inv_s = 1.0f / s;
        const float p2 = (e0 * e0 + e1 * e1 + e2 * e2 + e3 * e3) * inv_s * inv_s;
        wave_acc += -__logf(p2 + 1e-12f);
    }

    if (lane == 0) atomicAdd(out, wave_acc * scale);
}

extern "C" void kernel_launch(void* const* d_in, const int* in_sizes, int n_in,
                              void* d_out, int out_size, void* d_ws, size_t ws_size,
                              hipStream_t stream) {
    const float* feat_i  = (const float*)d_in[0];
    const float* coord_i = (const float*)d_in[1];
    const float* feat_j  = (const float*)d_in[2];
    const float* coord_j = (const float*)d_in[3];
    const int Ni = in_sizes[0] / 96;
    const int Nj = in_sizes[2] / 96;
    float* out = (float*)d_out;

    hipMemsetAsync(out, 0, sizeof(float), stream);

    {
        const int waves  = (Ni + QPW - 1) / QPW;
        const int blocks = (waves + WPB - 1) / WPB;
        knn_loss_kernel<<<blocks, 256, 0, stream>>>(coord_i, feat_i, Ni,
                                                    coord_j, feat_j, Nj,
                                                    0.5f / (float)Ni, out);
    }
    {
        const int waves  = (Nj + QPW - 1) / QPW;
        const int blocks = (waves + WPB - 1) / WPB;
        knn_loss_kernel<<<blocks, 256, 0, stream>>>(coord_j, feat_j, Nj,
                                                    coord_i, feat_i, Ni,
                                                    0.5f / (float)Nj, out);
    }
}

// Round 2
// 295.876 us; speedup vs baseline: 1.7537x; 1.7537x over previous
//
#include <hip/hip_runtime.h>
#include <math.h>

#define QPW 4   // queries per wave
#define WPB 4   // waves per block (block = 256)

__device__ __forceinline__ float wave_reduce_sum(float v) {
    #pragma unroll
    for (int off = 32; off >= 1; off >>= 1)
        v += __shfl_xor(v, off, 64);
    return v;
}

__device__ __forceinline__ void insert4(float d2, int p, float (&bd)[4], int (&bi)[4]) {
    if (d2 < bd[3]) {
        if (d2 < bd[2]) {
            bd[3] = bd[2]; bi[3] = bi[2];
            if (d2 < bd[1]) {
                bd[2] = bd[1]; bi[2] = bi[1];
                if (d2 < bd[0]) {
                    bd[1] = bd[0]; bi[1] = bi[0];
                    bd[0] = d2; bi[0] = p;
                } else { bd[1] = d2; bi[1] = p; }
            } else { bd[2] = d2; bi[2] = p; }
        } else { bd[3] = d2; bi[3] = p; }
    }
}

__global__ __launch_bounds__(256)
void knn_loss_fused(const float* __restrict__ cq0, const float* __restrict__ fq0, int Nq0,
                    const float* __restrict__ cd0, const float* __restrict__ fd0, int Nd0, float s0,
                    const float* __restrict__ cq1, const float* __restrict__ fq1, int Nq1,
                    const float* __restrict__ cd1, const float* __restrict__ fd1, int Nd1, float s1,
                    int B0, float* __restrict__ out)
{
    const int lane = threadIdx.x & 63;
    const int widx = threadIdx.x >> 6;

    const float *cq, *fq, *cd, *fd;
    int Nq, Nd, wave;
    float scale;
    if (blockIdx.x < B0) {
        cq = cq0; fq = fq0; Nq = Nq0; cd = cd0; fd = fd0; Nd = Nd0; scale = s0;
        wave = blockIdx.x * WPB + widx;
    } else {
        cq = cq1; fq = fq1; Nq = Nq1; cd = cd1; fd = fd1; Nd = Nd1; scale = s1;
        wave = (blockIdx.x - B0) * WPB + widx;
    }

    int qbase = wave * QPW;
    if (qbase >= Nq) return;
    qbase = __builtin_amdgcn_readfirstlane(qbase);

    // wave-uniform query coords (scalar loads)
    float qx[QPW], qy[QPW], qz[QPW];
    #pragma unroll
    for (int q = 0; q < QPW; ++q) {
        const int qi = (qbase + q < Nq) ? (qbase + q) : (Nq - 1);
        qx[q] = cq[qi * 3 + 0];
        qy[q] = cq[qi * 3 + 1];
        qz[q] = cq[qi * 3 + 2];
    }

    const float INF = 3.0e38f;
    float bd[QPW][4];
    int   bi[QPW][4];
    #pragma unroll
    for (int q = 0; q < QPW; ++q) {
        #pragma unroll
        for (int k = 0; k < 4; ++k) { bd[q][k] = INF; bi[q][k] = 0x7fffffff; }
    }

    // db scan: 128 points per iteration (2 per lane), unconditional clamped loads
    for (int base = 0; base < Nd; base += 128) {
        const int p0 = base + lane;
        const int p1 = base + 64 + lane;
        const int c0 = (p0 < Nd) ? p0 : (Nd - 1);
        const int c1 = (p1 < Nd) ? p1 : (Nd - 1);
        const float ax = cd[c0 * 3 + 0], ay = cd[c0 * 3 + 1], az = cd[c0 * 3 + 2];
        const float bx = cd[c1 * 3 + 0], by = cd[c1 * 3 + 1], bz = cd[c1 * 3 + 2];
        const bool v0 = (p0 < Nd), v1 = (p1 < Nd);

        #pragma unroll
        for (int q = 0; q < QPW; ++q) {
            float dx0 = ax - qx[q], dy0 = ay - qy[q], dz0 = az - qz[q];
            float dx1 = bx - qx[q], dy1 = by - qy[q], dz1 = bz - qz[q];
            float d20 = dx0 * dx0 + dy0 * dy0 + dz0 * dz0;
            float d21 = dx1 * dx1 + dy1 * dy1 + dz1 * dz1;
            if (!v0) d20 = INF;
            if (!v1) d21 = INF;
            insert4(d20, p0, bd[q], bi[q]);
            insert4(d21, p1, bd[q], bi[q]);
        }
    }

    float wave_acc = 0.0f;

    #pragma unroll
    for (int q = 0; q < QPW; ++q) {
        if (qbase + q >= Nq) break;

        // wave-wide merge: 4 rounds of lexicographic (d2, idx) min over lane heads
        int ni_[4];
        #pragma unroll
        for (int k = 0; k < 4; ++k) {
            float cdist = bd[q][0];
            int   cidx  = bi[q][0];
            #pragma unroll
            for (int off = 32; off >= 1; off >>= 1) {
                float od = __shfl_xor(cdist, off, 64);
                int   oi = __shfl_xor(cidx, off, 64);
                if (od < cdist || (od == cdist && oi < cidx)) { cdist = od; cidx = oi; }
            }
            ni_[k] = cidx;
            if (bi[q][0] == cidx) { // winning lane pops its head
                bd[q][0] = bd[q][1]; bi[q][0] = bi[q][1];
                bd[q][1] = bd[q][2]; bi[q][1] = bi[q][2];
                bd[q][2] = bd[q][3]; bi[q][2] = bi[q][3];
                bd[q][3] = INF;      bi[q][3] = 0x7fffffff;
            }
        }

        // cosine sims with fused normalization: 96 dims = lane + (64+lane for lane<32)
        const float* fqp = fq + (size_t)(qbase + q) * 96;
        const float  qf0 = fqp[lane];
        const float  qf1 = (lane < 32) ? fqp[64 + lane] : 0.0f;
        const float  ssq = wave_reduce_sum(qf0 * qf0 + qf1 * qf1);

        float sim[4];
        #pragma unroll
        for (int k = 0; k < 4; ++k) {
            const float* fdp = fd + (size_t)ni_[k] * 96;
            const float df0 = fdp[lane];
            const float df1 = (lane < 32) ? fdp[64 + lane] : 0.0f;
            const float dot = wave_reduce_sum(qf0 * df0 + qf1 * df1);
            const float ssd = wave_reduce_sum(df0 * df0 + df1 * df1);
            const float inv = rsqrtf(fmaxf(ssq, 1e-24f) * fmaxf(ssd, 1e-24f));
            sim[k] = dot * inv * 10.0f; // / TEMP
        }

        const float m = fmaxf(fmaxf(sim[0], sim[1]), fmaxf(sim[2], sim[3]));
        const float e0 = __expf(sim[0] - m);
        const float e1 = __expf(sim[1] - m);
        const float e2 = __expf(sim[2] - m);
        const float e3 = __expf(sim[3] - m);
        const float s  = e0 + e1 + e2 + e3;
        const float inv_s = 1.0f / s;
        const float p2 = (e0 * e0 + e1 * e1 + e2 * e2 + e3 * e3) * inv_s * inv_s;
        wave_acc += -__logf(p2 + 1e-12f);
    }

    if (lane == 0) atomicAdd(out, wave_acc * scale);
}

extern "C" void kernel_launch(void* const* d_in, const int* in_sizes, int n_in,
                              void* d_out, int out_size, void* d_ws, size_t ws_size,
                              hipStream_t stream) {
    const float* feat_i  = (const float*)d_in[0];
    const float* coord_i = (const float*)d_in[1];
    const float* feat_j  = (const float*)d_in[2];
    const float* coord_j = (const float*)d_in[3];
    const int Ni = in_sizes[0] / 96;
    const int Nj = in_sizes[2] / 96;
    float* out = (float*)d_out;

    hipMemsetAsync(out, 0, sizeof(float), stream);

    const int waves0  = (Ni + QPW - 1) / QPW;
    const int B0      = (waves0 + WPB - 1) / WPB;
    const int waves1  = (Nj + QPW - 1) / QPW;
    const int B1      = (waves1 + WPB - 1) / WPB;

    knn_loss_fused<<<B0 + B1, 256, 0, stream>>>(
        coord_i, feat_i, Ni, coord_j, feat_j, Nj, 0.5f / (float)Ni,
        coord_j, feat_j, Nj, coord_i, feat_i, Ni, 0.5f / (float)Nj,
        B0, out);
}

// Round 3
// 210.721 us; speedup vs baseline: 2.4624x; 1.4041x over previous
//
#include <hip/hip_runtime.h>
#include <math.h>

#define WPB 4   // waves per block (block = 256)

__device__ __forceinline__ float wave_reduce_sum(float v) {
    #pragma unroll
    for (int off = 32; off >= 1; off >>= 1)
        v += __shfl_xor(v, off, 64);
    return v;
}

__device__ __forceinline__ unsigned wave_min_u32(unsigned v) {
    #pragma unroll
    for (int off = 32; off >= 1; off >>= 1) {
        unsigned o = (unsigned)__shfl_xor((int)v, off, 64);
        v = (o < v) ? o : v;
    }
    return v;
}

// sorted ascending insert of packed key into 4-element list: 4 cmp + 7 cndmask
__device__ __forceinline__ void insert4u(unsigned k, unsigned (&b)[4]) {
    const bool c0 = k < b[0], c1 = k < b[1], c2 = k < b[2], c3 = k < b[3];
    b[3] = c2 ? b[2] : (c3 ? k : b[3]);
    b[2] = c1 ? b[1] : (c2 ? k : b[2]);
    b[1] = c0 ? b[0] : (c1 ? k : b[1]);
    b[0] = c0 ? k : b[0];
}

// key = (float_bits(d2) & 0xFFFF8000) | idx   (d2>=0 -> monotone; ties -> lower idx)
#define KMASK 0xFFFF8000u
#define IMASK 0x7FFFu

template<int QPW>
__device__ __forceinline__ void knn_dir(
    const float* __restrict__ cq, const float* __restrict__ fq, int Nq,
    const float* __restrict__ cd, const float* __restrict__ fd, int Nd,
    float scale, float* __restrict__ out, int blk)
{
    const int lane = threadIdx.x & 63;
    const int widx = threadIdx.x >> 6;
    int qbase = (blk * WPB + widx) * QPW;
    if (qbase >= Nq) return;
    qbase = __builtin_amdgcn_readfirstlane(qbase);

    // wave-uniform query coords
    float qx[QPW], qy[QPW], qz[QPW];
    #pragma unroll
    for (int q = 0; q < QPW; ++q) {
        const int qi = (qbase + q < Nq) ? (qbase + q) : (Nq - 1);
        qx[q] = cq[qi * 3 + 0];
        qy[q] = cq[qi * 3 + 1];
        qz[q] = cq[qi * 3 + 2];
    }

    unsigned bk[QPW][4];
    #pragma unroll
    for (int q = 0; q < QPW; ++q) {
        #pragma unroll
        for (int k = 0; k < 4; ++k) bk[q][k] = 0xFFFFFFFFu;
    }

    const int SEND = (Nd >= 1152) ? 1024 : 0;  // sample prefix (full batches guaranteed)

    const float* pc = cd + lane * 3;
    int idx0 = lane;

    // ---- phase A: unconditional inserts over first SEND points ----
    for (int base = 0; base < SEND; base += 128) {
        const float ax = pc[0],   ay = pc[1],   az = pc[2];
        const float bx = pc[192], by = pc[193], bz = pc[194];
        #pragma unroll
        for (int q = 0; q < QPW; ++q) {
            float dx = ax - qx[q], dy = ay - qy[q], dz = az - qz[q];
            float d2a = dx * dx + dy * dy + dz * dz;
            float ex = bx - qx[q], ey = by - qy[q], ez = bz - qz[q];
            float d2b = ex * ex + ey * ey + ez * ez;
            unsigned ka = (__float_as_uint(d2a) & KMASK) | (unsigned)idx0;
            unsigned kb = (__float_as_uint(d2b) & KMASK) | (unsigned)(idx0 + 64);
            insert4u(ka, bk[q]);
            insert4u(kb, bk[q]);
        }
        pc += 384;
        idx0 += 128;
    }

    // ---- per-query threshold = wave-wide 4th-smallest sample key ----
    unsigned thr[QPW];
    #pragma unroll
    for (int q = 0; q < QPW; ++q) {
        unsigned t0 = bk[q][0], t1 = bk[q][1], t2 = bk[q][2], t3 = bk[q][3];
        unsigned m = 0xFFFFFFFFu;
        #pragma unroll
        for (int r = 0; r < 4; ++r) {
            m = wave_min_u32(t0);
            const bool win = (t0 == m);
            t0 = win ? t1 : t0;
            t1 = win ? t2 : t1;
            t2 = win ? t3 : t2;
            t3 = win ? 0xFFFFFFFFu : t3;
        }
        thr[q] = m;
    }

    // ---- phase B: threshold-gated scan ----
    int base = SEND;
    for (; base + 128 <= Nd; base += 128) {
        const float ax = pc[0],   ay = pc[1],   az = pc[2];
        const float bx = pc[192], by = pc[193], bz = pc[194];
        #pragma unroll
        for (int q = 0; q < QPW; ++q) {
            float dx = ax - qx[q], dy = ay - qy[q], dz = az - qz[q];
            float d2a = dx * dx + dy * dy + dz * dz;
            unsigned ka = (__float_as_uint(d2a) & KMASK) | (unsigned)idx0;
            if (__any(ka < thr[q])) insert4u(ka, bk[q]);
            float ex = bx - qx[q], ey = by - qy[q], ez = bz - qz[q];
            float d2b = ex * ex + ey * ey + ez * ez;
            unsigned kb = (__float_as_uint(d2b) & KMASK) | (unsigned)(idx0 + 64);
            if (__any(kb < thr[q])) insert4u(kb, bk[q]);
        }
        pc += 384;
        idx0 += 128;
    }

    // ---- tail (< 128 points): clamped loads, invalid -> UINT_MAX key ----
    if (base < Nd) {
        const int p0 = base + lane, p1 = p0 + 64;
        const int c0 = (p0 < Nd) ? p0 : (Nd - 1);
        const int c1 = (p1 < Nd) ? p1 : (Nd - 1);
        const float ax = cd[c0 * 3], ay = cd[c0 * 3 + 1], az = cd[c0 * 3 + 2];
        const float bx = cd[c1 * 3], by = cd[c1 * 3 + 1], bz = cd[c1 * 3 + 2];
        #pragma unroll
        for (int q = 0; q < QPW; ++q) {
            float dx = ax - qx[q], dy = ay - qy[q], dz = az - qz[q];
            float d2a = dx * dx + dy * dy + dz * dz;
            float ex = bx - qx[q], ey = by - qy[q], ez = bz - qz[q];
            float d2b = ex * ex + ey * ey + ez * ez;
            unsigned ka = (__float_as_uint(d2a) & KMASK) | (unsigned)p0;
            unsigned kb = (__float_as_uint(d2b) & KMASK) | (unsigned)p1;
            if (p0 >= Nd) ka = 0xFFFFFFFFu;
            if (p1 >= Nd) kb = 0xFFFFFFFFu;
            insert4u(ka, bk[q]);
            insert4u(kb, bk[q]);
        }
    }

    // ---- merge + epilogue ----
    float wave_acc = 0.0f;

    #pragma unroll
    for (int q = 0; q < QPW; ++q) {
        if (qbase + q >= Nq) break;

        unsigned t0 = bk[q][0], t1 = bk[q][1], t2 = bk[q][2], t3 = bk[q][3];
        int ni[4];
        #pragma unroll
        for (int k = 0; k < 4; ++k) {
            const unsigned m = wave_min_u32(t0);
            ni[k] = (int)(m & IMASK);
            const bool win = (t0 == m);
            t0 = win ? t1 : t0;
            t1 = win ? t2 : t1;
            t2 = win ? t3 : t2;
            t3 = win ? 0xFFFFFFFFu : t3;
        }

        // cosine sims with fused normalization: 96 dims = lane + (64+lane for lane<32)
        const float* fqp = fq + (size_t)(qbase + q) * 96;
        const float  qf0 = fqp[lane];
        const float  qf1 = (lane < 32) ? fqp[64 + lane] : 0.0f;
        const float  ssq = wave_reduce_sum(qf0 * qf0 + qf1 * qf1);

        float sim[4];
        #pragma unroll
        for (int k = 0; k < 4; ++k) {
            const float* fdp = fd + (size_t)ni[k] * 96;
            const float df0 = fdp[lane];
            const float df1 = (lane < 32) ? fdp[64 + lane] : 0.0f;
            const float dot = wave_reduce_sum(qf0 * df0 + qf1 * df1);
            const float ssd = wave_reduce_sum(df0 * df0 + df1 * df1);
            const float inv = rsqrtf(fmaxf(ssq, 1e-24f) * fmaxf(ssd, 1e-24f));
            sim[k] = dot * inv * 10.0f; // / TEMP
        }

        const float m = fmaxf(fmaxf(sim[0], sim[1]), fmaxf(sim[2], sim[3]));
        const float e0 = __expf(sim[0] - m);
        const float e1 = __expf(sim[1] - m);
        const float e2 = __expf(sim[2] - m);
        const float e3 = __expf(sim[3] - m);
        const float s  = e0 + e1 + e2 + e3;
        const float inv_s = 1.0f / s;
        const float p2 = (e0 * e0 + e1 * e1 + e2 * e2 + e3 * e3) * inv_s * inv_s;
        wave_acc += -__logf(p2 + 1e-12f);
    }

    if (lane == 0) atomicAdd(out, wave_acc * scale);
}

__global__ __launch_bounds__(256)
void knn_loss_fused(const float* __restrict__ ci, const float* __restrict__ fi, int Ni,
                    const float* __restrict__ cj, const float* __restrict__ fj, int Nj,
                    float s0, float s1, int B0, float* __restrict__ out)
{
    if ((int)blockIdx.x < B0)
        knn_dir<4>(ci, fi, Ni, cj, fj, Nj, s0, out, blockIdx.x);          // i queries vs j db
    else
        knn_dir<4>(cj, fj, Nj, ci, fi, Ni, s1, out, blockIdx.x - B0);     // j queries vs i db
}

extern "C" void kernel_launch(void* const* d_in, const int* in_sizes, int n_in,
                              void* d_out, int out_size, void* d_ws, size_t ws_size,
                              hipStream_t stream) {
    const float* feat_i  = (const float*)d_in[0];
    const float* coord_i = (const float*)d_in[1];
    const float* feat_j  = (const float*)d_in[2];
    const float* coord_j = (const float*)d_in[3];
    const int Ni = in_sizes[0] / 96;
    const int Nj = in_sizes[2] / 96;
    float* out = (float*)d_out;

    hipMemsetAsync(out, 0, sizeof(float), stream);

    const int waves0 = (Ni + 3) / 4;
    const int B0     = (waves0 + WPB - 1) / WPB;
    const int waves1 = (Nj + 3) / 4;
    const int B1     = (waves1 + WPB - 1) / WPB;

    knn_loss_fused<<<B0 + B1, 256, 0, stream>>>(
        coord_i, feat_i, Ni, coord_j, feat_j, Nj,
        0.5f / (float)Ni, 0.5f / (float)Nj, B0, out);
}

// Round 4
// 175.187 us; speedup vs baseline: 2.9618x; 1.2028x over previous
//
#include <hip/hip_runtime.h>
#include <math.h>

#define WPB 4   // waves per block (block = 256)

__device__ __forceinline__ float wave_reduce_sum(float v) {
    #pragma unroll
    for (int off = 32; off >= 1; off >>= 1)
        v += __shfl_xor(v, off, 64);
    return v;
}

__device__ __forceinline__ unsigned wave_min_u32(unsigned v) {
    #pragma unroll
    for (int off = 32; off >= 1; off >>= 1) {
        unsigned o = (unsigned)__shfl_xor((int)v, off, 64);
        v = (o < v) ? o : v;
    }
    return v;
}

// sorted ascending insert of packed key into 4-element list: 4 cmp + 7 cndmask
__device__ __forceinline__ void insert4u(unsigned k, unsigned (&b)[4]) {
    const bool c0 = k < b[0], c1 = k < b[1], c2 = k < b[2], c3 = k < b[3];
    b[3] = c2 ? b[2] : (c3 ? k : b[3]);
    b[2] = c1 ? b[1] : (c2 ? k : b[2]);
    b[1] = c0 ? b[0] : (c1 ? k : b[1]);
    b[0] = c0 ? k : b[0];
}

// key = (float_bits(d2) & 0xFFFF8000) | idx   (d2>=0 -> monotone; ties -> lower idx)
#define KMASK 0xFFFF8000u
#define IMASK 0x7FFFu

template<int QPW>
__device__ __forceinline__ void knn_dir(
    const float* __restrict__ cq, const float* __restrict__ fq, int Nq,
    const float* __restrict__ cd, const float* __restrict__ fd, int Nd,
    float scale, float* __restrict__ out, int blk)
{
    const int lane = threadIdx.x & 63;
    const int widx = threadIdx.x >> 6;
    int qbase = (blk * WPB + widx) * QPW;
    if (qbase >= Nq) return;
    qbase = __builtin_amdgcn_readfirstlane(qbase);

    // wave-uniform query coords
    float qx[QPW], qy[QPW], qz[QPW];
    #pragma unroll
    for (int q = 0; q < QPW; ++q) {
        const int qi = (qbase + q < Nq) ? (qbase + q) : (Nq - 1);
        qx[q] = cq[qi * 3 + 0];
        qy[q] = cq[qi * 3 + 1];
        qz[q] = cq[qi * 3 + 2];
    }

    unsigned bk[QPW][4];
    #pragma unroll
    for (int q = 0; q < QPW; ++q) {
        #pragma unroll
        for (int k = 0; k < 4; ++k) bk[q][k] = 0xFFFFFFFFu;
    }

    const int SEND = (Nd >= 1152) ? 1024 : 0;  // sample prefix (full batches guaranteed)

    const float* pc = cd + lane * 3;
    int idx0 = lane;

    // ---- phase A: unconditional inserts over first SEND points (packed f32 pairs) ----
    for (int base = 0; base < SEND; base += 128) {
        const float ax = pc[0],   ay = pc[1],   az = pc[2];
        const float bx = pc[192], by = pc[193], bz = pc[194];
        #pragma unroll
        for (int q = 0; q < QPW; ++q) {
            const float dxa = ax - qx[q], dya = ay - qy[q], dza = az - qz[q];
            const float dxb = bx - qx[q], dyb = by - qy[q], dzb = bz - qz[q];
            const float d2a = dxa * dxa + dya * dya + dza * dza;
            const float d2b = dxb * dxb + dyb * dyb + dzb * dzb;
            unsigned ka = (__float_as_uint(d2a) & KMASK) | (unsigned)idx0;
            unsigned kb = (__float_as_uint(d2b) & KMASK) | (unsigned)(idx0 + 64);
            insert4u(ka, bk[q]);
            insert4u(kb, bk[q]);
        }
        pc += 384;
        idx0 += 128;
    }

    // ---- per-query float threshold = upper bound of 4th-smallest sample key ----
    float thrf[QPW];
    #pragma unroll
    for (int q = 0; q < QPW; ++q) {
        unsigned t0 = bk[q][0], t1 = bk[q][1], t2 = bk[q][2], t3 = bk[q][3];
        unsigned m = 0xFFFFFFFFu;
        #pragma unroll
        for (int r = 0; r < 4; ++r) {
            m = wave_min_u32(t0);
            const bool win = (t0 == m);
            t0 = win ? t1 : t0;
            t1 = win ? t2 : t1;
            t2 = win ? t3 : t2;
            t3 = win ? 0xFFFFFFFFu : t3;
        }
        // max float consistent with truncated key (superset gate); clamp NaN/inf -> FLT_MAX
        unsigned ub = m | IMASK;
        if (ub >= 0x7F800000u) ub = 0x7F7FFFFFu;
        thrf[q] = __uint_as_float(ub);
    }

    // ---- phase B: threshold-gated scan; pack+insert only when gate fires ----
    int base = SEND;
    for (; base + 128 <= Nd; base += 128) {
        const float ax = pc[0],   ay = pc[1],   az = pc[2];
        const float bx = pc[192], by = pc[193], bz = pc[194];
        #pragma unroll
        for (int q = 0; q < QPW; ++q) {
            const float dxa = ax - qx[q], dya = ay - qy[q], dza = az - qz[q];
            const float dxb = bx - qx[q], dyb = by - qy[q], dzb = bz - qz[q];
            const float d2a = dxa * dxa + dya * dya + dza * dza;
            const float d2b = dxb * dxb + dyb * dyb + dzb * dzb;
            if (__any(fminf(d2a, d2b) <= thrf[q])) {
                unsigned ka = (__float_as_uint(d2a) & KMASK) | (unsigned)idx0;
                unsigned kb = (__float_as_uint(d2b) & KMASK) | (unsigned)(idx0 + 64);
                insert4u(ka, bk[q]);
                insert4u(kb, bk[q]);
            }
        }
        pc += 384;
        idx0 += 128;
    }

    // ---- tail (< 128 points): clamped loads, invalid -> UINT_MAX key ----
    if (base < Nd) {
        const int p0 = base + lane, p1 = p0 + 64;
        const int c0 = (p0 < Nd) ? p0 : (Nd - 1);
        const int c1 = (p1 < Nd) ? p1 : (Nd - 1);
        const float ax = cd[c0 * 3], ay = cd[c0 * 3 + 1], az = cd[c0 * 3 + 2];
        const float bx = cd[c1 * 3], by = cd[c1 * 3 + 1], bz = cd[c1 * 3 + 2];
        #pragma unroll
        for (int q = 0; q < QPW; ++q) {
            const float dxa = ax - qx[q], dya = ay - qy[q], dza = az - qz[q];
            const float dxb = bx - qx[q], dyb = by - qy[q], dzb = bz - qz[q];
            const float d2a = dxa * dxa + dya * dya + dza * dza;
            const float d2b = dxb * dxb + dyb * dyb + dzb * dzb;
            unsigned ka = (__float_as_uint(d2a) & KMASK) | (unsigned)p0;
            unsigned kb = (__float_as_uint(d2b) & KMASK) | (unsigned)p1;
            if (p0 >= Nd) ka = 0xFFFFFFFFu;
            if (p1 >= Nd) kb = 0xFFFFFFFFu;
            insert4u(ka, bk[q]);
            insert4u(kb, bk[q]);
        }
    }

    // ---- merge + epilogue ----
    float wave_acc = 0.0f;

    #pragma unroll
    for (int q = 0; q < QPW; ++q) {
        if (qbase + q >= Nq) break;

        unsigned t0 = bk[q][0], t1 = bk[q][1], t2 = bk[q][2], t3 = bk[q][3];
        int ni[4];
        #pragma unroll
        for (int k = 0; k < 4; ++k) {
            const unsigned m = wave_min_u32(t0);
            ni[k] = (int)(m & IMASK);
            const bool win = (t0 == m);
            t0 = win ? t1 : t0;
            t1 = win ? t2 : t1;
            t2 = win ? t3 : t2;
            t3 = win ? 0xFFFFFFFFu : t3;
        }

        // cosine sims with fused normalization: 96 dims = lane + (64+lane for lane<32)
        const float* fqp = fq + (size_t)(qbase + q) * 96;
        const float  qf0 = fqp[lane];
        const float  qf1 = (lane < 32) ? fqp[64 + lane] : 0.0f;
        const float  ssq = wave_reduce_sum(qf0 * qf0 + qf1 * qf1);

        float sim[4];
        #pragma unroll
        for (int k = 0; k < 4; ++k) {
            const float* fdp = fd + (size_t)ni[k] * 96;
            const float df0 = fdp[lane];
            const float df1 = (lane < 32) ? fdp[64 + lane] : 0.0f;
            const float dot = wave_reduce_sum(qf0 * df0 + qf1 * df1);
            const float ssd = wave_reduce_sum(df0 * df0 + df1 * df1);
            const float inv = rsqrtf(fmaxf(ssq, 1e-24f) * fmaxf(ssd, 1e-24f));
            sim[k] = dot * inv * 10.0f; // / TEMP
        }

        const float m = fmaxf(fmaxf(sim[0], sim[1]), fmaxf(sim[2], sim[3]));
        const float e0 = __expf(sim[0] - m);
        const float e1 = __expf(sim[1] - m);
        const float e2 = __expf(sim[2] - m);
        const float e3 = __expf(sim[3] - m);
        const float s  = e0 + e1 + e2 + e3;
        const float inv_s = 1.0f / s;
        const float p2 = (e0 * e0 + e1 * e1 + e2 * e2 + e3 * e3) * inv_s * inv_s;
        wave_acc += -__logf(p2 + 1e-12f);
    }

    if (lane == 0) atomicAdd(out, wave_acc * scale);
}

__global__ __launch_bounds__(256)
void knn_loss_fused(const float* __restrict__ ci, const float* __restrict__ fi, int Ni,
                    const float* __restrict__ cj, const float* __restrict__ fj, int Nj,
                    float s0, float s1, int B0, int B1, float* __restrict__ out)
{
    // interleave dir0/dir1 blocks so long and short work mixes across CUs
    const int bid = (int)blockIdx.x;
    const int bmin = (B0 < B1) ? B0 : B1;
    int dir, blk;
    if (bid < 2 * bmin) { dir = bid & 1; blk = bid >> 1; }
    else { dir = (B0 > B1) ? 0 : 1; blk = bid - 2 * bmin + bmin; }

    if (dir == 0)
        knn_dir<8>(ci, fi, Ni, cj, fj, Nj, s0, out, blk);   // i queries vs j db
    else
        knn_dir<4>(cj, fj, Nj, ci, fi, Ni, s1, out, blk);   // j queries vs i db
}

extern "C" void kernel_launch(void* const* d_in, const int* in_sizes, int n_in,
                              void* d_out, int out_size, void* d_ws, size_t ws_size,
                              hipStream_t stream) {
    const float* feat_i  = (const float*)d_in[0];
    const float* coord_i = (const float*)d_in[1];
    const float* feat_j  = (const float*)d_in[2];
    const float* coord_j = (const float*)d_in[3];
    const int Ni = in_sizes[0] / 96;
    const int Nj = in_sizes[2] / 96;
    float* out = (float*)d_out;

    hipMemsetAsync(out, 0, sizeof(float), stream);

    const int waves0 = (Ni + 7) / 8;           // dir0: QPW=8
    const int B0     = (waves0 + WPB - 1) / WPB;
    const int waves1 = (Nj + 3) / 4;           // dir1: QPW=4
    const int B1     = (waves1 + WPB - 1) / WPB;

    knn_loss_fused<<<B0 + B1, 256, 0, stream>>>(
        coord_i, feat_i, Ni, coord_j, feat_j, Nj,
        0.5f / (float)Ni, 0.5f / (float)Nj, B0, B1, out);
}

// Round 5
// 169.548 us; speedup vs baseline: 3.0603x; 1.0333x over previous
//
#include <hip/hip_runtime.h>
#include <math.h>

#define WPB 2   // waves per block (block = 128 threads)

__device__ __forceinline__ float wave_reduce_sum(float v) {
    #pragma unroll
    for (int off = 32; off >= 1; off >>= 1) v += __shfl_xor(v, off, 64);
    return v;
}

__device__ __forceinline__ unsigned wave_min_u32(unsigned v) {
    #pragma unroll
    for (int off = 32; off >= 1; off >>= 1) {
        unsigned o = (unsigned)__shfl_xor((int)v, off, 64);
        v = (o < v) ? o : v;
    }
    return v;
}

__device__ __forceinline__ float wave_min_f32(float v) {
    #pragma unroll
    for (int off = 32; off >= 1; off >>= 1) v = fminf(v, __shfl_xor(v, off, 64));
    return v;
}

// sorted ascending insert of packed key into 4-element list: 4 cmp + 7 cndmask
__device__ __forceinline__ void insert4u(unsigned k, unsigned (&b)[4]) {
    const bool c0 = k < b[0], c1 = k < b[1], c2 = k < b[2], c3 = k < b[3];
    b[3] = c2 ? b[2] : (c3 ? k : b[3]);
    b[2] = c1 ? b[1] : (c2 ? k : b[2]);
    b[1] = c0 ? b[0] : (c1 ? k : b[1]);
    b[0] = c0 ? k : b[0];
}

// key = (float_bits(d2) & KMASK) | idx  (d2>=0 -> unsigned-monotone; ties -> lower idx)
#define KMASK 0xFFFF8000u
#define IMASK 0x7FFFu

// prep: [N][3] -> [N]{x,y,z,|p|^2}
__global__ __launch_bounds__(256)
void pack_coords(const float* __restrict__ c, float4* __restrict__ o, int n) {
    const int i = blockIdx.x * 256 + threadIdx.x;
    if (i < n) {
        const float x = c[3 * i], y = c[3 * i + 1], z = c[3 * i + 2];
        o[i] = make_float4(x, y, z, x * x + y * y + z * z);
    }
}

template<int QPW, bool PACKED>
__device__ __forceinline__ void knn_dir(
    const float* __restrict__ cq, const float* __restrict__ fq, int Nq,
    const float4* __restrict__ d4, const float* __restrict__ cdraw,
    const float* __restrict__ fd, int Nd,
    float scale, float* __restrict__ out, int blk)
{
    const int lane = threadIdx.x & 63;
    const int widx = threadIdx.x >> 6;
    int qbase = (blk * WPB + widx) * QPW;
    if (qbase >= Nq) return;
    qbase = __builtin_amdgcn_readfirstlane(qbase);

    // wave-uniform query constants: d2'(p) = pw - 2 q.p  (ordering == true d2 per q)
    float m2x[QPW], m2y[QPW], m2z[QPW], qq[QPW];
    #pragma unroll
    for (int q = 0; q < QPW; ++q) {
        const int qi = (qbase + q < Nq) ? (qbase + q) : (Nq - 1);
        const float x = cq[qi * 3], y = cq[qi * 3 + 1], z = cq[qi * 3 + 2];
        m2x[q] = -2.0f * x; m2y[q] = -2.0f * y; m2z[q] = -2.0f * z;
        qq[q] = x * x + y * y + z * z;
    }

    auto loadp = [&](int i) -> float4 {
        if constexpr (PACKED) {
            return d4[i];
        } else {
            const float x = cdraw[3 * i], y = cdraw[3 * i + 1], z = cdraw[3 * i + 2];
            return make_float4(x, y, z, x * x + y * y + z * z);
        }
    };
    auto d2p = [&](const float4& P, int q) -> float {
        return fmaf(P.z, m2z[q], fmaf(P.y, m2y[q], fmaf(P.x, m2x[q], P.w)));
    };

    // ---- sample pass: per-lane minimum d2' over first SB*128 points ----
    const int SB = ((Nd >> 7) < 16) ? (Nd >> 7) : 16;
    float smin[QPW];
    #pragma unroll
    for (int q = 0; q < QPW; ++q) smin[q] = 3.0e38f;

    int off = lane;
    for (int b = 0; b < SB; ++b) {
        const float4 A = loadp(off);
        const float4 B = loadp(off + 64);
        #pragma unroll
        for (int q = 0; q < QPW; ++q)
            smin[q] = fminf(smin[q], fminf(d2p(A, q), d2p(B, q)));
        off += 128;
    }

    // thr[q] = 4th-smallest of the 64 lane minima (valid upper bound of global 4th)
    float thr[QPW];
    #pragma unroll
    for (int q = 0; q < QPW; ++q) {
        float v = smin[q], m = 3.0e38f;
        #pragma unroll
        for (int r = 0; r < 4; ++r) {
            m = wave_min_f32(v);
            v = (v == m) ? 3.0e38f : v;
        }
        thr[q] = m;
    }

    // ---- full gated scan over all Nd points ----
    unsigned bk[QPW][4];
    #pragma unroll
    for (int q = 0; q < QPW; ++q) {
        #pragma unroll
        for (int k = 0; k < 4; ++k) bk[q][k] = 0xFFFFFFFFu;
    }

    off = lane;
    int idx0 = lane;
    const int nb = Nd >> 7;
    for (int b = 0; b < nb; ++b) {
        const float4 A = loadp(off);
        const float4 B = loadp(off + 64);
        #pragma unroll
        for (int q = 0; q < QPW; ++q) {
            const float d2a = d2p(A, q);
            const float d2b = d2p(B, q);
            if (__any(d2a <= thr[q])) {
                const unsigned ka =
                    (__float_as_uint(fmaxf(d2a + qq[q], 0.0f)) & KMASK) | (unsigned)idx0;
                insert4u(ka, bk[q]);
            }
            if (__any(d2b <= thr[q])) {
                const unsigned kb =
                    (__float_as_uint(fmaxf(d2b + qq[q], 0.0f)) & KMASK) | (unsigned)(idx0 + 64);
                insert4u(kb, bk[q]);
            }
        }
        off += 128;
        idx0 += 128;
    }

    // ---- tail (< 128 points): clamped loads, invalid -> UINT_MAX, unconditional insert ----
    const int base = nb << 7;
    if (base < Nd) {
        const int p0 = base + lane, p1 = p0 + 64;
        const int c0 = (p0 < Nd) ? p0 : (Nd - 1);
        const int c1 = (p1 < Nd) ? p1 : (Nd - 1);
        const float4 A = loadp(c0);
        const float4 B = loadp(c1);
        #pragma unroll
        for (int q = 0; q < QPW; ++q) {
            const float d2a = d2p(A, q);
            const float d2b = d2p(B, q);
            unsigned ka = (__float_as_uint(fmaxf(d2a + qq[q], 0.0f)) & KMASK) | (unsigned)c0;
            unsigned kb = (__float_as_uint(fmaxf(d2b + qq[q], 0.0f)) & KMASK) | (unsigned)c1;
            if (p0 >= Nd) ka = 0xFFFFFFFFu;
            if (p1 >= Nd) kb = 0xFFFFFFFFu;
            insert4u(ka, bk[q]);
            insert4u(kb, bk[q]);
        }
    }

    // ---- merge + epilogue ----
    float wave_acc = 0.0f;

    #pragma unroll
    for (int q = 0; q < QPW; ++q) {
        if (qbase + q >= Nq) break;

        unsigned t0 = bk[q][0], t1 = bk[q][1], t2 = bk[q][2], t3 = bk[q][3];
        int ni[4];
        #pragma unroll
        for (int k = 0; k < 4; ++k) {
            const unsigned m = wave_min_u32(t0);
            ni[k] = (int)(m & IMASK);
            const bool win = (t0 == m);
            t0 = win ? t1 : t0;
            t1 = win ? t2 : t1;
            t2 = win ? t3 : t2;
            t3 = win ? 0xFFFFFFFFu : t3;
        }

        // cosine sims with fused normalization: 96 dims = lane + (64+lane for lane<32)
        const float* fqp = fq + (size_t)(qbase + q) * 96;
        const float  qf0 = fqp[lane];
        const float  qf1 = (lane < 32) ? fqp[64 + lane] : 0.0f;
        const float  ssq = wave_reduce_sum(qf0 * qf0 + qf1 * qf1);

        float sim[4];
        #pragma unroll
        for (int k = 0; k < 4; ++k) {
            const float* fdp = fd + (size_t)ni[k] * 96;
            const float df0 = fdp[lane];
            const float df1 = (lane < 32) ? fdp[64 + lane] : 0.0f;
            const float dot = wave_reduce_sum(qf0 * df0 + qf1 * df1);
            const float ssd = wave_reduce_sum(df0 * df0 + df1 * df1);
            const float inv = rsqrtf(fmaxf(ssq, 1e-24f) * fmaxf(ssd, 1e-24f));
            sim[k] = dot * inv * 10.0f; // / TEMP
        }

        const float m = fmaxf(fmaxf(sim[0], sim[1]), fmaxf(sim[2], sim[3]));
        const float e0 = __expf(sim[0] - m);
        const float e1 = __expf(sim[1] - m);
        const float e2 = __expf(sim[2] - m);
        const float e3 = __expf(sim[3] - m);
        const float s  = e0 + e1 + e2 + e3;
        const float inv_s = 1.0f / s;
        const float p2 = (e0 * e0 + e1 * e1 + e2 * e2 + e3 * e3) * inv_s * inv_s;
        wave_acc += -__logf(p2 + 1e-12f);
    }

    if (lane == 0) atomicAdd(out, wave_acc * scale);
}

template<bool PACKED>
__global__ __launch_bounds__(128)
void knn_loss_fused(const float* __restrict__ ci, const float* __restrict__ fi, int Ni,
                    const float* __restrict__ cj, const float* __restrict__ fj, int Nj,
                    const float4* __restrict__ c4i, const float4* __restrict__ c4j,
                    float s0, float s1, int B0, int B1, float* __restrict__ out)
{
    // interleave dir0/dir1 blocks so work mixes across CUs
    const int bid = (int)blockIdx.x;
    const int bmin = (B0 < B1) ? B0 : B1;
    int dir, blk;
    if (bid < 2 * bmin) { dir = bid & 1; blk = bid >> 1; }
    else { dir = (B0 > B1) ? 0 : 1; blk = bid - bmin; }

    if (dir == 0)
        knn_dir<8, PACKED>(ci, fi, Ni, c4j, cj, fj, Nj, s0, out, blk);  // i queries vs j db
    else
        knn_dir<4, PACKED>(cj, fj, Nj, c4i, ci, fi, Ni, s1, out, blk);  // j queries vs i db
}

extern "C" void kernel_launch(void* const* d_in, const int* in_sizes, int n_in,
                              void* d_out, int out_size, void* d_ws, size_t ws_size,
                              hipStream_t stream) {
    const float* feat_i  = (const float*)d_in[0];
    const float* coord_i = (const float*)d_in[1];
    const float* feat_j  = (const float*)d_in[2];
    const float* coord_j = (const float*)d_in[3];
    const int Ni = in_sizes[0] / 96;
    const int Nj = in_sizes[2] / 96;
    float* out = (float*)d_out;

    hipMemsetAsync(out, 0, sizeof(float), stream);

    const int waves0 = (Ni + 7) / 8;           // dir0: QPW=8
    const int B0     = (waves0 + WPB - 1) / WPB;
    const int waves1 = (Nj + 3) / 4;           // dir1: QPW=4
    const int B1     = (waves1 + WPB - 1) / WPB;

    const size_t need = (size_t)(Ni + Nj) * sizeof(float4);
    if (ws_size >= need) {
        float4* c4i = (float4*)d_ws;
        float4* c4j = c4i + Ni;
        pack_coords<<<(Ni + 255) / 256, 256, 0, stream>>>(coord_i, c4i, Ni);
        pack_coords<<<(Nj + 255) / 256, 256, 0, stream>>>(coord_j, c4j, Nj);
        knn_loss_fused<true><<<B0 + B1, 128, 0, stream>>>(
            coord_i, feat_i, Ni, coord_j, feat_j, Nj, c4i, c4j,
            0.5f / (float)Ni, 0.5f / (float)Nj, B0, B1, out);
    } else {
        knn_loss_fused<false><<<B0 + B1, 128, 0, stream>>>(
            coord_i, feat_i, Ni, coord_j, feat_j, Nj, nullptr, nullptr,
            0.5f / (float)Ni, 0.5f / (float)Nj, B0, B1, out);
    }
}

// Round 6
// 169.376 us; speedup vs baseline: 3.0634x; 1.0010x over previous
//
#include <hip/hip_runtime.h>
#include <math.h>

#define WPB 2   // waves per block (block = 128 threads)

__device__ __forceinline__ float wave_reduce_sum(float v) {
    #pragma unroll
    for (int off = 32; off >= 1; off >>= 1) v += __shfl_xor(v, off, 64);
    return v;
}

__device__ __forceinline__ unsigned wave_min_u32(unsigned v) {
    #pragma unroll
    for (int off = 32; off >= 1; off >>= 1) {
        unsigned o = (unsigned)__shfl_xor((int)v, off, 64);
        v = (o < v) ? o : v;
    }
    return v;
}

__device__ __forceinline__ float wave_min_f32(float v) {
    #pragma unroll
    for (int off = 32; off >= 1; off >>= 1) v = fminf(v, __shfl_xor(v, off, 64));
    return v;
}

// sorted ascending insert of packed key into 4-element list: 4 cmp + 7 cndmask
__device__ __forceinline__ void insert4u(unsigned k, unsigned (&b)[4]) {
    const bool c0 = k < b[0], c1 = k < b[1], c2 = k < b[2], c3 = k < b[3];
    b[3] = c2 ? b[2] : (c3 ? k : b[3]);
    b[2] = c1 ? b[1] : (c2 ? k : b[2]);
    b[1] = c0 ? b[0] : (c1 ? k : b[1]);
    b[0] = c0 ? k : b[0];
}

// key = (float_bits(d2) & KMASK) | idx  (d2>=0 -> unsigned-monotone; ties -> lower idx)
#define KMASK 0xFFFF8000u
#define IMASK 0x7FFFu

// prep: [N][3] -> [N]{x,y,z,|p|^2}
__global__ __launch_bounds__(256)
void pack_coords(const float* __restrict__ c, float4* __restrict__ o, int n) {
    const int i = blockIdx.x * 256 + threadIdx.x;
    if (i < n) {
        const float x = c[3 * i], y = c[3 * i + 1], z = c[3 * i + 2];
        o[i] = make_float4(x, y, z, x * x + y * y + z * z);
    }
}

template<int QPW, bool PACKED>
__device__ __forceinline__ void knn_dir(
    const float* __restrict__ cq, const float* __restrict__ fq, int Nq,
    const float4* __restrict__ d4, const float* __restrict__ cdraw,
    const float* __restrict__ fd, int Nd,
    float scale, float* __restrict__ out, int blk)
{
    const int lane = threadIdx.x & 63;
    const int widx = threadIdx.x >> 6;
    int qbase = (blk * WPB + widx) * QPW;
    if (qbase >= Nq) return;
    qbase = __builtin_amdgcn_readfirstlane(qbase);

    // wave-uniform query constants: d2'(p) = pw - 2 q.p  (ordering == true d2 per q)
    float m2x[QPW], m2y[QPW], m2z[QPW], qq[QPW];
    #pragma unroll
    for (int q = 0; q < QPW; ++q) {
        const int qi = (qbase + q < Nq) ? (qbase + q) : (Nq - 1);
        const float x = cq[qi * 3], y = cq[qi * 3 + 1], z = cq[qi * 3 + 2];
        m2x[q] = -2.0f * x; m2y[q] = -2.0f * y; m2z[q] = -2.0f * z;
        qq[q] = x * x + y * y + z * z;
    }

    auto loadp = [&](int i) -> float4 {
        if constexpr (PACKED) {
            return d4[i];
        } else {
            const float x = cdraw[3 * i], y = cdraw[3 * i + 1], z = cdraw[3 * i + 2];
            return make_float4(x, y, z, x * x + y * y + z * z);
        }
    };
    auto d2p = [&](const float4& P, int q) -> float {
        return fmaf(P.z, m2z[q], fmaf(P.y, m2y[q], fmaf(P.x, m2x[q], P.w)));
    };

    // ---- sample pass: per-lane minimum d2' over first SB*128 points ----
    const int SB = ((Nd >> 7) < 16) ? (Nd >> 7) : 16;
    float smin[QPW];
    #pragma unroll
    for (int q = 0; q < QPW; ++q) smin[q] = 3.0e38f;

    int off = lane;
    for (int b = 0; b < SB; ++b) {
        const float4 A = loadp(off);
        const float4 B = loadp(off + 64);
        #pragma unroll
        for (int q = 0; q < QPW; ++q)
            smin[q] = fminf(smin[q], fminf(d2p(A, q), d2p(B, q)));
        off += 128;
    }

    // thr[q] = 4th-smallest of the 64 lane minima (valid upper bound of global 4th)
    float thr[QPW];
    #pragma unroll
    for (int q = 0; q < QPW; ++q) {
        float v = smin[q], m = 3.0e38f;
        #pragma unroll
        for (int r = 0; r < 4; ++r) {
            m = wave_min_f32(v);
            v = (v == m) ? 3.0e38f : v;
        }
        thr[q] = m;
    }

    // ---- full gated scan over all Nd points ----
    unsigned bk[QPW][4];
    #pragma unroll
    for (int q = 0; q < QPW; ++q) {
        #pragma unroll
        for (int k = 0; k < 4; ++k) bk[q][k] = 0xFFFFFFFFu;
    }

    off = lane;
    int idx0 = lane;
    const int nb = Nd >> 7;
    for (int b = 0; b < nb; ++b) {
        const float4 A = loadp(off);
        const float4 B = loadp(off + 64);
        #pragma unroll
        for (int q = 0; q < QPW; ++q) {
            const float d2a = d2p(A, q);
            const float d2b = d2p(B, q);
            if (__any(d2a <= thr[q])) {
                asm volatile("");  // side effect: forbid if-conversion / speculation
                const unsigned ka =
                    (__float_as_uint(fmaxf(d2a + qq[q], 0.0f)) & KMASK) | (unsigned)idx0;
                insert4u(ka, bk[q]);
            }
            if (__any(d2b <= thr[q])) {
                asm volatile("");
                const unsigned kb =
                    (__float_as_uint(fmaxf(d2b + qq[q], 0.0f)) & KMASK) | (unsigned)(idx0 + 64);
                insert4u(kb, bk[q]);
            }
        }
        off += 128;
        idx0 += 128;
    }

    // ---- tail (< 128 points): clamped loads, invalid -> UINT_MAX, unconditional insert ----
    const int base = nb << 7;
    if (base < Nd) {
        const int p0 = base + lane, p1 = p0 + 64;
        const int c0 = (p0 < Nd) ? p0 : (Nd - 1);
        const int c1 = (p1 < Nd) ? p1 : (Nd - 1);
        const float4 A = loadp(c0);
        const float4 B = loadp(c1);
        #pragma unroll
        for (int q = 0; q < QPW; ++q) {
            const float d2a = d2p(A, q);
            const float d2b = d2p(B, q);
            unsigned ka = (__float_as_uint(fmaxf(d2a + qq[q], 0.0f)) & KMASK) | (unsigned)c0;
            unsigned kb = (__float_as_uint(fmaxf(d2b + qq[q], 0.0f)) & KMASK) | (unsigned)c1;
            if (p0 >= Nd) ka = 0xFFFFFFFFu;
            if (p1 >= Nd) kb = 0xFFFFFFFFu;
            insert4u(ka, bk[q]);
            insert4u(kb, bk[q]);
        }
    }

    // ---- merge + epilogue ----
    float wave_acc = 0.0f;

    #pragma unroll
    for (int q = 0; q < QPW; ++q) {
        if (qbase + q >= Nq) break;

        unsigned t0 = bk[q][0], t1 = bk[q][1], t2 = bk[q][2], t3 = bk[q][3];
        int ni[4];
        #pragma unroll
        for (int k = 0; k < 4; ++k) {
            const unsigned m = wave_min_u32(t0);
            ni[k] = (int)(m & IMASK);
            const bool win = (t0 == m);
            t0 = win ? t1 : t0;
            t1 = win ? t2 : t1;
            t2 = win ? t3 : t2;
            t3 = win ? 0xFFFFFFFFu : t3;
        }

        // cosine sims with fused normalization: 96 dims = lane + (64+lane for lane<32)
        const float* fqp = fq + (size_t)(qbase + q) * 96;
        const float  qf0 = fqp[lane];
        const float  qf1 = (lane < 32) ? fqp[64 + lane] : 0.0f;
        const float  ssq = wave_reduce_sum(qf0 * qf0 + qf1 * qf1);

        float sim[4];
        #pragma unroll
        for (int k = 0; k < 4; ++k) {
            const float* fdp = fd + (size_t)ni[k] * 96;
            const float df0 = fdp[lane];
            const float df1 = (lane < 32) ? fdp[64 + lane] : 0.0f;
            const float dot = wave_reduce_sum(qf0 * df0 + qf1 * df1);
            const float ssd = wave_reduce_sum(df0 * df0 + df1 * df1);
            const float inv = rsqrtf(fmaxf(ssq, 1e-24f) * fmaxf(ssd, 1e-24f));
            sim[k] = dot * inv * 10.0f; // / TEMP
        }

        const float m = fmaxf(fmaxf(sim[0], sim[1]), fmaxf(sim[2], sim[3]));
        const float e0 = __expf(sim[0] - m);
        const float e1 = __expf(sim[1] - m);
        const float e2 = __expf(sim[2] - m);
        const float e3 = __expf(sim[3] - m);
        const float s  = e0 + e1 + e2 + e3;
        const float inv_s = 1.0f / s;
        const float p2 = (e0 * e0 + e1 * e1 + e2 * e2 + e3 * e3) * inv_s * inv_s;
        wave_acc += -__logf(p2 + 1e-12f);
    }

    if (lane == 0) atomicAdd(out, wave_acc * scale);
}

template<bool PACKED>
__global__ __launch_bounds__(128)
void knn_loss_fused(const float* __restrict__ ci, const float* __restrict__ fi, int Ni,
                    const float* __restrict__ cj, const float* __restrict__ fj, int Nj,
                    const float4* __restrict__ c4i, const float4* __restrict__ c4j,
                    float s0, float s1, int B0, int B1, float* __restrict__ out)
{
    // interleave dir0/dir1 blocks so work mixes across CUs
    const int bid = (int)blockIdx.x;
    const int bmin = (B0 < B1) ? B0 : B1;
    int dir, blk;
    if (bid < 2 * bmin) { dir = bid & 1; blk = bid >> 1; }
    else { dir = (B0 > B1) ? 0 : 1; blk = bid - bmin; }

    if (dir == 0)
        knn_dir<8, PACKED>(ci, fi, Ni, c4j, cj, fj, Nj, s0, out, blk);  // i queries vs j db
    else
        knn_dir<4, PACKED>(cj, fj, Nj, c4i, ci, fi, Ni, s1, out, blk);  // j queries vs i db
}

extern "C" void kernel_launch(void* const* d_in, const int* in_sizes, int n_in,
                              void* d_out, int out_size, void* d_ws, size_t ws_size,
                              hipStream_t stream) {
    const float* feat_i  = (const float*)d_in[0];
    const float* coord_i = (const float*)d_in[1];
    const float* feat_j  = (const float*)d_in[2];
    const float* coord_j = (const float*)d_in[3];
    const int Ni = in_sizes[0] / 96;
    const int Nj = in_sizes[2] / 96;
    float* out = (float*)d_out;

    hipMemsetAsync(out, 0, sizeof(float), stream);

    const int waves0 = (Ni + 7) / 8;           // dir0: QPW=8
    const int B0     = (waves0 + WPB - 1) / WPB;
    const int waves1 = (Nj + 3) / 4;           // dir1: QPW=4
    const int B1     = (waves1 + WPB - 1) / WPB;

    const size_t need = (size_t)(Ni + Nj) * sizeof(float4);
    if (ws_size >= need) {
        float4* c4i = (float4*)d_ws;
        float4* c4j = c4i + Ni;
        pack_coords<<<(Ni + 255) / 256, 256, 0, stream>>>(coord_i, c4i, Ni);
        pack_coords<<<(Nj + 255) / 256, 256, 0, stream>>>(coord_j, c4j, Nj);
        knn_loss_fused<true><<<B0 + B1, 128, 0, stream>>>(
            coord_i, feat_i, Ni, coord_j, feat_j, Nj, c4i, c4j,
            0.5f / (float)Ni, 0.5f / (float)Nj, B0, B1, out);
    } else {
        knn_loss_fused<false><<<B0 + B1, 128, 0, stream>>>(
            coord_i, feat_i, Ni, coord_j, feat_j, Nj, nullptr, nullptr,
            0.5f / (float)Ni, 0.5f / (float)Nj, B0, B1, out);
    }
}

// Round 7
// 86.889 us; speedup vs baseline: 5.9717x; 1.9493x over previous
//
#include <hip/hip_runtime.h>
#include <math.h>

#define KMASK 0xFFFF8000u
#define IMASK 0x7FFFu

__device__ __forceinline__ float wave_reduce_sum(float v) {
    #pragma unroll
    for (int off = 32; off >= 1; off >>= 1) v += __shfl_xor(v, off, 64);
    return v;
}

__device__ __forceinline__ unsigned wave_min_u32(unsigned v) {
    #pragma unroll
    for (int off = 32; off >= 1; off >>= 1) {
        unsigned o = (unsigned)__shfl_xor((int)v, off, 64);
        v = (o < v) ? o : v;
    }
    return v;
}

// min over aligned 8-lane group (xor 4,2,1 stays in-group)
__device__ __forceinline__ unsigned gmin8(unsigned v) {
    #pragma unroll
    for (int off = 4; off >= 1; off >>= 1) {
        unsigned o = (unsigned)__shfl_xor((int)v, off, 64);
        v = (o < v) ? o : v;
    }
    return v;
}

// sorted ascending insert of packed key into 4-element list
__device__ __forceinline__ void insert4u(unsigned k, unsigned (&b)[4]) {
    const bool c0 = k < b[0], c1 = k < b[1], c2 = k < b[2], c3 = k < b[3];
    b[3] = c2 ? b[2] : (c3 ? k : b[3]);
    b[2] = c1 ? b[1] : (c2 ? k : b[2]);
    b[1] = c0 ? b[0] : (c1 ? k : b[1]);
    b[0] = c0 ? k : b[0];
}

__device__ __forceinline__ int cell_of(float x, int G) {
    int c = (int)(x * (float)G);
    return (c < 0) ? 0 : ((c >= G) ? G - 1 : c);
}

// ============================ grid build ============================

__global__ __launch_bounds__(256)
void grid_count(const float* __restrict__ cA, int nA, int GA, int* __restrict__ stA,
                const float* __restrict__ cB, int nB, int GB, int* __restrict__ stB)
{
    const int t = blockIdx.x * 256 + threadIdx.x;
    const float* c; int* s; int G; int p;
    if (t < nA)           { c = cA; s = stA; G = GA; p = t; }
    else if (t < nA + nB) { c = cB; s = stB; G = GB; p = t - nA; }
    else return;
    const int cx = cell_of(c[3*p], G), cy = cell_of(c[3*p+1], G), cz = cell_of(c[3*p+2], G);
    atomicAdd(&s[(cz * G + cy) * G + cx + 1], 1);
}

// in-place inclusive scan of s[0..n] (n+1 elements); block 256
__global__ __launch_bounds__(256)
void grid_scan(int* __restrict__ sA, int nA, int* __restrict__ sB, int nB)
{
    int* s = blockIdx.x ? sB : sA;
    const int n = blockIdx.x ? nB : nA;
    __shared__ int part[256];
    const int t = threadIdx.x;
    const int len = n + 1;
    const int chunk = (len + 255) >> 8;
    const int lo = t * chunk;
    const int hi = (lo + chunk < len) ? (lo + chunk) : len;
    int sum = 0;
    for (int i = lo; i < hi; ++i) sum += s[i];
    part[t] = sum;
    __syncthreads();
    for (int d = 1; d < 256; d <<= 1) {
        const int v = (t >= d) ? part[t - d] : 0;
        __syncthreads();
        part[t] += v;
        __syncthreads();
    }
    int run = (t > 0) ? part[t - 1] : 0;
    for (int i = lo; i < hi; ++i) { run += s[i]; s[i] = run; }
}

__global__ __launch_bounds__(256)
void grid_scatter(const float* __restrict__ cA, int nA, int GA, int* __restrict__ cuA,
                  float4* __restrict__ soA, int* __restrict__ siA,
                  const float* __restrict__ cB, int nB, int GB, int* __restrict__ cuB,
                  float4* __restrict__ soB, int* __restrict__ siB)
{
    const int t = blockIdx.x * 256 + threadIdx.x;
    const float* c; int* cu; float4* so; int* si; int G; int p;
    if (t < nA)           { c = cA; cu = cuA; so = soA; si = siA; G = GA; p = t; }
    else if (t < nA + nB) { c = cB; cu = cuB; so = soB; si = siB; G = GB; p = t - nA; }
    else return;
    const float x = c[3*p], y = c[3*p+1], z = c[3*p+2];
    const int cx = cell_of(x, G), cy = cell_of(y, G), cz = cell_of(z, G);
    const int pos = atomicAdd(&cu[(cz * G + cy) * G + cx], 1);
    so[pos] = make_float4(x, y, z, x*x + y*y + z*z);
    si[pos] = p;
}

// ============================ grid KNN ============================
// 8 lanes per query. Exact: expands box until r4^2 <= margin^2 (or full cover).

__device__ __forceinline__ int4 knn_group(
    float qx, float qy, float qz,
    const float4* __restrict__ pts, const int* __restrict__ starts,
    const int* __restrict__ sidx, int G, int nd, int sub)
{
    const float h = 1.0f / (float)G;
    const int cx = cell_of(qx, G), cy = cell_of(qy, G), cz = cell_of(qz, G);
    const float qq  = qx*qx + qy*qy + qz*qz;
    const float m2x = -2.0f*qx, m2y = -2.0f*qy, m2z = -2.0f*qz;
    unsigned mk0 = ~0u, mk1 = ~0u, mk2 = ~0u, mk3 = ~0u;

    for (int s = 1; ; ++s) {
        const int x0 = max(cx - s, 0), x1 = min(cx + s, G - 1);
        const int y0 = max(cy - s, 0), y1 = min(cy + s, G - 1);
        const int z0 = max(cz - s, 0), z1 = min(cz + s, G - 1);

        unsigned bk[4] = {~0u, ~0u, ~0u, ~0u};
        for (int z = z0; z <= z1; ++z) {
            for (int y = y0; y <= y1; ++y) {
                const int rb = (z * G + y) * G;
                const int cs = starts[rb + x0];
                const int ce = starts[rb + x1 + 1];
                for (int c = cs + sub; c < ce; c += 8) {
                    const float4 P = pts[c];
                    const float d2 =
                        fmaf(P.z, m2z, fmaf(P.y, m2y, fmaf(P.x, m2x, P.w))) + qq;
                    const unsigned k =
                        (__float_as_uint(fmaxf(d2, 0.0f)) & KMASK) | (unsigned)c;
                    insert4u(k, bk);
                }
            }
        }

        unsigned t0 = bk[0], t1 = bk[1], t2 = bk[2], t3 = bk[3];
        #pragma unroll
        for (int r = 0; r < 4; ++r) {
            const unsigned m = gmin8(t0);
            if (r == 0) mk0 = m; else if (r == 1) mk1 = m;
            else if (r == 2) mk2 = m; else mk3 = m;
            const bool win = (t0 == m);
            t0 = win ? t1 : t0;
            t1 = win ? t2 : t1;
            t2 = win ? t3 : t2;
            t3 = win ? ~0u : t3;
        }

        // margin to nearest non-domain-boundary face of the searched box
        float margin = 3.0e38f;
        if (x0 > 0)     margin = fminf(margin, qx - (float)x0 * h);
        if (x1 < G - 1) margin = fminf(margin, (float)(x1 + 1) * h - qx);
        if (y0 > 0)     margin = fminf(margin, qy - (float)y0 * h);
        if (y1 < G - 1) margin = fminf(margin, (float)(y1 + 1) * h - qy);
        if (z0 > 0)     margin = fminf(margin, qz - (float)z0 * h);
        if (z1 < G - 1) margin = fminf(margin, (float)(z1 + 1) * h - qz);
        const bool covered = (margin > 1.0e37f);
        const float kd = __uint_as_float(mk3 & KMASK);   // NaN-bits if <4 found
        if (covered || (kd * 1.01f <= margin * margin)) break;  // NaN -> expand
    }
    const int nm1 = nd - 1;
    return make_int4(sidx[min((int)(mk0 & IMASK), nm1)],
                     sidx[min((int)(mk1 & IMASK), nm1)],
                     sidx[min((int)(mk2 & IMASK), nm1)],
                     sidx[min((int)(mk3 & IMASK), nm1)]);
}

__global__ __launch_bounds__(256)
void grid_knn(const float* __restrict__ ci, int Ni, const float* __restrict__ cj, int Nj,
              const float4* __restrict__ soA, const int* __restrict__ stA,
              const int* __restrict__ siA, int GA, int ndA,
              const float4* __restrict__ soB, const int* __restrict__ stB,
              const int* __restrict__ siB, int GB, int ndB,
              int4* __restrict__ nbr)
{
    const int sub = threadIdx.x & 7;
    const int qid = (blockIdx.x * 256 + threadIdx.x) >> 3;
    if (qid >= Ni + Nj) return;
    int4 r;
    if (qid < Ni) {
        const float x = ci[3*qid], y = ci[3*qid+1], z = ci[3*qid+2];
        r = knn_group(x, y, z, soA, stA, siA, GA, ndA, sub);
    } else {
        const int p = qid - Ni;
        const float x = cj[3*p], y = cj[3*p+1], z = cj[3*p+2];
        r = knn_group(x, y, z, soB, stB, siB, GB, ndB, sub);
    }
    if (sub == 0) nbr[qid] = r;
}

// ============================ epilogue ============================

__global__ __launch_bounds__(256)
void epilogue(const float* __restrict__ fi, int Ni, const float* __restrict__ fj, int Nj,
              const int4* __restrict__ nbr, float sc0, float sc1,
              float* __restrict__ partial)
{
    const int lane = threadIdx.x & 63;
    const int w = threadIdx.x >> 6;
    const int qid = blockIdx.x * 4 + w;
    float acc = 0.0f;
    if (qid < Ni + Nj) {
        const bool d0 = (qid < Ni);
        const float* fqp = d0 ? (fi + (size_t)qid * 96) : (fj + (size_t)(qid - Ni) * 96);
        const float* fd  = d0 ? fj : fi;
        const float scale = d0 ? sc0 : sc1;
        const int4 nb = nbr[qid];
        const int ni_[4] = {nb.x, nb.y, nb.z, nb.w};

        const float qf0 = fqp[lane];
        const float qf1 = (lane < 32) ? fqp[64 + lane] : 0.0f;
        const float ssq = wave_reduce_sum(qf0 * qf0 + qf1 * qf1);

        float sim[4];
        #pragma unroll
        for (int k = 0; k < 4; ++k) {
            const float* fdp = fd + (size_t)ni_[k] * 96;
            const float df0 = fdp[lane];
            const float df1 = (lane < 32) ? fdp[64 + lane] : 0.0f;
            const float dot = wave_reduce_sum(qf0 * df0 + qf1 * df1);
            const float ssd = wave_reduce_sum(df0 * df0 + df1 * df1);
            sim[k] = dot * rsqrtf(fmaxf(ssq, 1e-24f) * fmaxf(ssd, 1e-24f)) * 10.0f;
        }
        const float m = fmaxf(fmaxf(sim[0], sim[1]), fmaxf(sim[2], sim[3]));
        const float e0 = __expf(sim[0] - m), e1 = __expf(sim[1] - m);
        const float e2 = __expf(sim[2] - m), e3 = __expf(sim[3] - m);
        const float ssum = e0 + e1 + e2 + e3;
        const float inv = 1.0f / ssum;
        const float p2 = (e0*e0 + e1*e1 + e2*e2 + e3*e3) * inv * inv;
        acc = -__logf(p2 + 1e-12f) * scale;
    }
    __shared__ float red[4];
    if (lane == 0) red[w] = acc;
    __syncthreads();
    if (threadIdx.x == 0)
        atomicAdd(&partial[blockIdx.x & 63], red[0] + red[1] + red[2] + red[3]);
}

__global__ __launch_bounds__(64)
void final_sum(const float* __restrict__ partial, float* __restrict__ out) {
    float v = partial[threadIdx.x];
    v = wave_reduce_sum(v);
    if (threadIdx.x == 0) out[0] = v;
}

// ============================ brute fallback ============================

#define WPB 4
template<int QPW>
__device__ __forceinline__ void brute_dir(
    const float* __restrict__ cq, const float* __restrict__ fq, int Nq,
    const float* __restrict__ cd, const float* __restrict__ fd, int Nd,
    float scale, float* __restrict__ out, int blk)
{
    const int lane = threadIdx.x & 63;
    const int widx = threadIdx.x >> 6;
    int qbase = (blk * WPB + widx) * QPW;
    if (qbase >= Nq) return;
    qbase = __builtin_amdgcn_readfirstlane(qbase);

    float qx[QPW], qy[QPW], qz[QPW];
    #pragma unroll
    for (int q = 0; q < QPW; ++q) {
        const int qi = (qbase + q < Nq) ? (qbase + q) : (Nq - 1);
        qx[q] = cq[qi*3]; qy[q] = cq[qi*3+1]; qz[q] = cq[qi*3+2];
    }
    unsigned bk[QPW][4];
    #pragma unroll
    for (int q = 0; q < QPW; ++q) {
        #pragma unroll
        for (int k = 0; k < 4; ++k) bk[q][k] = ~0u;
    }
    for (int base = 0; base < Nd; base += 64) {
        const int p = base + lane;
        const int cp = (p < Nd) ? p : (Nd - 1);
        const float px = cd[cp*3], py = cd[cp*3+1], pz = cd[cp*3+2];
        #pragma unroll
        for (int q = 0; q < QPW; ++q) {
            const float dx = px - qx[q], dy = py - qy[q], dz = pz - qz[q];
            const float d2 = dx*dx + dy*dy + dz*dz;
            unsigned k = (__float_as_uint(d2) & KMASK) | (unsigned)p;
            if (p >= Nd) k = ~0u;
            insert4u(k, bk[q]);
        }
    }
    float wacc = 0.0f;
    #pragma unroll
    for (int q = 0; q < QPW; ++q) {
        if (qbase + q >= Nq) break;
        unsigned t0 = bk[q][0], t1 = bk[q][1], t2 = bk[q][2], t3 = bk[q][3];
        int ni_[4];
        #pragma unroll
        for (int k = 0; k < 4; ++k) {
            const unsigned m = wave_min_u32(t0);
            ni_[k] = (int)(m & IMASK);
            const bool win = (t0 == m);
            t0 = win ? t1 : t0; t1 = win ? t2 : t1; t2 = win ? t3 : t2; t3 = win ? ~0u : t3;
        }
        const float* fqp = fq + (size_t)(qbase + q) * 96;
        const float qf0 = fqp[lane];
        const float qf1 = (lane < 32) ? fqp[64 + lane] : 0.0f;
        const float ssq = wave_reduce_sum(qf0*qf0 + qf1*qf1);
        float sim[4];
        #pragma unroll
        for (int k = 0; k < 4; ++k) {
            const float* fdp = fd + (size_t)ni_[k] * 96;
            const float df0 = fdp[lane];
            const float df1 = (lane < 32) ? fdp[64 + lane] : 0.0f;
            const float dot = wave_reduce_sum(qf0*df0 + qf1*df1);
            const float ssd = wave_reduce_sum(df0*df0 + df1*df1);
            sim[k] = dot * rsqrtf(fmaxf(ssq, 1e-24f) * fmaxf(ssd, 1e-24f)) * 10.0f;
        }
        const float m = fmaxf(fmaxf(sim[0], sim[1]), fmaxf(sim[2], sim[3]));
        const float e0 = __expf(sim[0]-m), e1 = __expf(sim[1]-m);
        const float e2 = __expf(sim[2]-m), e3 = __expf(sim[3]-m);
        const float ssum = e0+e1+e2+e3;
        const float inv = 1.0f/ssum;
        const float p2 = (e0*e0+e1*e1+e2*e2+e3*e3)*inv*inv;
        wacc += -__logf(p2 + 1e-12f);
    }
    if (lane == 0) atomicAdd(out, wacc * scale);
}

__global__ __launch_bounds__(256)
void brute_fused(const float* __restrict__ ci, const float* __restrict__ fi, int Ni,
                 const float* __restrict__ cj, const float* __restrict__ fj, int Nj,
                 float s0, float s1, int B0, int B1, float* __restrict__ out)
{
    const int bid = (int)blockIdx.x;
    const int bmin = (B0 < B1) ? B0 : B1;
    int dir, blk;
    if (bid < 2 * bmin) { dir = bid & 1; blk = bid >> 1; }
    else { dir = (B0 > B1) ? 0 : 1; blk = bid - bmin; }
    if (dir == 0) brute_dir<8>(ci, fi, Ni, cj, fj, Nj, s0, out, blk);
    else          brute_dir<4>(cj, fj, Nj, ci, fi, Ni, s1, out, blk);
}

// ============================ launch ============================

extern "C" void kernel_launch(void* const* d_in, const int* in_sizes, int n_in,
                              void* d_out, int out_size, void* d_ws, size_t ws_size,
                              hipStream_t stream) {
    const float* feat_i  = (const float*)d_in[0];
    const float* coord_i = (const float*)d_in[1];
    const float* feat_j  = (const float*)d_in[2];
    const float* coord_j = (const float*)d_in[3];
    const int Ni = in_sizes[0] / 96;
    const int Nj = in_sizes[2] / 96;
    float* out = (float*)d_out;

    auto gridfor = [](int n) {
        int g = (int)cbrtf((float)n / 4.5f);
        if (g < 2) g = 2;
        if (g > 28) g = 28;
        return g;
    };
    const int GA = gridfor(Nj), GB = gridfor(Ni);       // A: db=j, B: db=i
    const int GA3 = GA * GA * GA, GB3 = GB * GB * GB;

    size_t off = 0;
    auto alloc = [&](size_t bytes) { size_t o = off; off = (off + bytes + 15) & ~(size_t)15; return o; };
    const size_t o_soA  = alloc((size_t)Nj * 16);
    const size_t o_soB  = alloc((size_t)Ni * 16);
    const size_t o_nbr  = alloc((size_t)(Ni + Nj) * 16);
    const size_t o_siA  = alloc((size_t)Nj * 4);
    const size_t o_siB  = alloc((size_t)Ni * 4);
    const size_t o_stA  = alloc((size_t)(GA3 + 1) * 4);
    const size_t o_stB  = alloc((size_t)(GB3 + 1) * 4);
    const size_t o_cuA  = alloc((size_t)GA3 * 4);
    const size_t o_cuB  = alloc((size_t)GB3 * 4);
    const size_t o_part = alloc(64 * 4);

    if (ws_size >= off && Ni >= 8 && Nj >= 8 && Ni <= 32000 && Nj <= 32000) {
        char* W = (char*)d_ws;
        float4* soA = (float4*)(W + o_soA);
        float4* soB = (float4*)(W + o_soB);
        int4*   nbr = (int4*)(W + o_nbr);
        int* siA = (int*)(W + o_siA);
        int* siB = (int*)(W + o_siB);
        int* stA = (int*)(W + o_stA);
        int* stB = (int*)(W + o_stB);
        int* cuA = (int*)(W + o_cuA);
        int* cuB = (int*)(W + o_cuB);
        float* part = (float*)(W + o_part);

        hipMemsetAsync(stA, 0, (size_t)(GA3 + 1) * 4, stream);
        hipMemsetAsync(stB, 0, (size_t)(GB3 + 1) * 4, stream);
        hipMemsetAsync(part, 0, 64 * 4, stream);

        const int nPts = Ni + Nj;
        grid_count<<<(nPts + 255) / 256, 256, 0, stream>>>(
            coord_j, Nj, GA, stA, coord_i, Ni, GB, stB);
        grid_scan<<<2, 256, 0, stream>>>(stA, GA3, stB, GB3);
        hipMemcpyAsync(cuA, stA, (size_t)GA3 * 4, hipMemcpyDeviceToDevice, stream);
        hipMemcpyAsync(cuB, stB, (size_t)GB3 * 4, hipMemcpyDeviceToDevice, stream);
        grid_scatter<<<(nPts + 255) / 256, 256, 0, stream>>>(
            coord_j, Nj, GA, cuA, soA, siA, coord_i, Ni, GB, cuB, soB, siB);

        const int nQ = Ni + Nj;
        grid_knn<<<(nQ * 8 + 255) / 256, 256, 0, stream>>>(
            coord_i, Ni, coord_j, Nj,
            soA, stA, siA, GA, Nj,
            soB, stB, siB, GB, Ni,
            nbr);
        epilogue<<<(nQ + 3) / 4, 256, 0, stream>>>(
            feat_i, Ni, feat_j, Nj, nbr, 0.5f / (float)Ni, 0.5f / (float)Nj, part);
        final_sum<<<1, 64, 0, stream>>>(part, out);
    } else {
        hipMemsetAsync(out, 0, sizeof(float), stream);
        const int waves0 = (Ni + 7) / 8;
        const int B0 = (waves0 + WPB - 1) / WPB;
        const int waves1 = (Nj + 3) / 4;
        const int B1 = (waves1 + WPB - 1) / WPB;
        brute_fused<<<B0 + B1, 256, 0, stream>>>(
            coord_i, feat_i, Ni, coord_j, feat_j, Nj,
            0.5f / (float)Ni, 0.5f / (float)Nj, B0, B1, out);
    }
}

// Round 8
// 63.183 us; speedup vs baseline: 8.2122x; 1.3752x over previous
//
#include <hip/hip_runtime.h>
#include <math.h>

#define KMASK 0xFFFF8000u
#define IMASK 0x7FFFu

__device__ __forceinline__ float wave_reduce_sum(float v) {
    #pragma unroll
    for (int off = 32; off >= 1; off >>= 1) v += __shfl_xor(v, off, 64);
    return v;
}

__device__ __forceinline__ unsigned wave_min_u32(unsigned v) {
    #pragma unroll
    for (int off = 32; off >= 1; off >>= 1) {
        unsigned o = (unsigned)__shfl_xor((int)v, off, 64);
        v = (o < v) ? o : v;
    }
    return v;
}

// reduce over aligned 8-lane group (xor 4,2,1 stays in-group)
__device__ __forceinline__ unsigned gmin8(unsigned v) {
    #pragma unroll
    for (int off = 4; off >= 1; off >>= 1) {
        unsigned o = (unsigned)__shfl_xor((int)v, off, 64);
        v = (o < v) ? o : v;
    }
    return v;
}
__device__ __forceinline__ float gsum8(float v) {
    #pragma unroll
    for (int off = 4; off >= 1; off >>= 1) v += __shfl_xor(v, off, 64);
    return v;
}

// sorted ascending insert of packed key into 4-element list
__device__ __forceinline__ void insert4u(unsigned k, unsigned (&b)[4]) {
    const bool c0 = k < b[0], c1 = k < b[1], c2 = k < b[2], c3 = k < b[3];
    b[3] = c2 ? b[2] : (c3 ? k : b[3]);
    b[2] = c1 ? b[1] : (c2 ? k : b[2]);
    b[1] = c0 ? b[0] : (c1 ? k : b[1]);
    b[0] = c0 ? k : b[0];
}

__device__ __forceinline__ int cell_of(float x, int G) {
    int c = (int)(x * (float)G);
    return (c < 0) ? 0 : ((c >= G) ? G - 1 : c);
}

__device__ __forceinline__ float dot4(float4 a, float4 b) {
    return fmaf(a.w, b.w, fmaf(a.z, b.z, fmaf(a.y, b.y, a.x * b.x)));
}

// ============================ grid build ============================

__global__ __launch_bounds__(256)
void grid_zero(int* __restrict__ stA, int nA, int* __restrict__ stB, int nB,
               float* __restrict__ part)
{
    const int t = blockIdx.x * 256 + threadIdx.x;
    if (t < nA) stA[t] = 0;
    if (t < nB) stB[t] = 0;
    if (t < 64) part[t] = 0.0f;
}

__global__ __launch_bounds__(256)
void grid_count(const float* __restrict__ cA, int nA, int GA, int* __restrict__ stA,
                const float* __restrict__ cB, int nB, int GB, int* __restrict__ stB)
{
    const int t = blockIdx.x * 256 + threadIdx.x;
    const float* c; int* s; int G; int p;
    if (t < nA)           { c = cA; s = stA; G = GA; p = t; }
    else if (t < nA + nB) { c = cB; s = stB; G = GB; p = t - nA; }
    else return;
    const int cx = cell_of(c[3*p], G), cy = cell_of(c[3*p+1], G), cz = cell_of(c[3*p+2], G);
    atomicAdd(&s[(cz * G + cy) * G + cx + 1], 1);
}

// in-place inclusive scan of s[0..n]; also writes cu[i] = s[i] (cell starts)
__global__ __launch_bounds__(256)
void grid_scan(int* __restrict__ sA, int nA, int* __restrict__ cuA,
               int* __restrict__ sB, int nB, int* __restrict__ cuB)
{
    int* s  = blockIdx.x ? sB  : sA;
    int* cu = blockIdx.x ? cuB : cuA;
    const int n = blockIdx.x ? nB : nA;
    __shared__ int part[256];
    const int t = threadIdx.x;
    const int len = n + 1;
    const int chunk = (len + 255) >> 8;
    const int lo = t * chunk;
    const int hi = (lo + chunk < len) ? (lo + chunk) : len;
    int sum = 0;
    for (int i = lo; i < hi; ++i) sum += s[i];
    part[t] = sum;
    __syncthreads();
    for (int d = 1; d < 256; d <<= 1) {
        const int v = (t >= d) ? part[t - d] : 0;
        __syncthreads();
        part[t] += v;
        __syncthreads();
    }
    int run = (t > 0) ? part[t - 1] : 0;
    for (int i = lo; i < hi; ++i) {
        run += s[i];
        s[i] = run;
        if (i < n) cu[i] = run;
    }
}

__global__ __launch_bounds__(256)
void grid_scatter(const float* __restrict__ cA, int nA, int GA, int* __restrict__ cuA,
                  float4* __restrict__ soA, int* __restrict__ siA,
                  const float* __restrict__ cB, int nB, int GB, int* __restrict__ cuB,
                  float4* __restrict__ soB, int* __restrict__ siB)
{
    const int t = blockIdx.x * 256 + threadIdx.x;
    const float* c; int* cu; float4* so; int* si; int G; int p;
    if (t < nA)           { c = cA; cu = cuA; so = soA; si = siA; G = GA; p = t; }
    else if (t < nA + nB) { c = cB; cu = cuB; so = soB; si = siB; G = GB; p = t - nA; }
    else return;
    const float x = c[3*p], y = c[3*p+1], z = c[3*p+2];
    const int cx = cell_of(x, G), cy = cell_of(y, G), cz = cell_of(z, G);
    const int pos = atomicAdd(&cu[(cz * G + cy) * G + cx], 1);
    so[pos] = make_float4(x, y, z, x*x + y*y + z*z);
    si[pos] = p;
}

// ==================== fused grid KNN + loss ====================
// 8 lanes per query: exact KNN (expand box until r4^2 <= margin^2 or full
// cover), then the same 8 lanes compute the cosine/softmax loss.

__global__ __launch_bounds__(256)
void knnloss(const float* __restrict__ ci, const float* __restrict__ fi, int Ni,
             const float* __restrict__ cj, const float* __restrict__ fj, int Nj,
             const float4* __restrict__ soA, const int* __restrict__ stA,
             const int* __restrict__ siA, int GA,
             const float4* __restrict__ soB, const int* __restrict__ stB,
             const int* __restrict__ siB, int GB,
             float sc0, float sc1, float* __restrict__ partial)
{
    const int sub = threadIdx.x & 7;
    const int qid = (blockIdx.x * 256 + threadIdx.x) >> 3;
    float acc = 0.0f;

    if (qid < Ni + Nj) {
        const bool d0 = (qid < Ni);
        const int p = d0 ? qid : qid - Ni;
        const float*  cq = d0 ? ci  : cj;
        const float4* so = d0 ? soA : soB;
        const int*    st = d0 ? stA : stB;
        const int*    si = d0 ? siA : siB;
        const int      G = d0 ? GA  : GB;
        const int     nd = d0 ? Nj  : Ni;
        const float* fqp = (d0 ? fi : fj) + (size_t)p * 96;
        const float*  fd = d0 ? fj : fi;
        const float scale = d0 ? sc0 : sc1;

        const float qx = cq[3*p], qy = cq[3*p+1], qz = cq[3*p+2];
        const float h = 1.0f / (float)G;
        const int cx = cell_of(qx, G), cy = cell_of(qy, G), cz = cell_of(qz, G);
        const float qq  = qx*qx + qy*qy + qz*qz;
        const float m2x = -2.0f*qx, m2y = -2.0f*qy, m2z = -2.0f*qz;
        unsigned mk0 = ~0u, mk1 = ~0u, mk2 = ~0u, mk3 = ~0u;

        for (int s = 1; ; ++s) {
            const int x0 = max(cx - s, 0), x1 = min(cx + s, G - 1);
            const int y0 = max(cy - s, 0), y1 = min(cy + s, G - 1);
            const int z0 = max(cz - s, 0), z1 = min(cz + s, G - 1);

            unsigned bk[4] = {~0u, ~0u, ~0u, ~0u};
            for (int z = z0; z <= z1; ++z) {
                for (int y = y0; y <= y1; ++y) {
                    const int rb = (z * G + y) * G;
                    const int cs = st[rb + x0];
                    const int ce = st[rb + x1 + 1];
                    for (int c = cs + sub; c < ce; c += 8) {
                        const float4 P = so[c];
                        const float d2 =
                            fmaf(P.z, m2z, fmaf(P.y, m2y, fmaf(P.x, m2x, P.w))) + qq;
                        const unsigned k =
                            (__float_as_uint(fmaxf(d2, 0.0f)) & KMASK) | (unsigned)c;
                        insert4u(k, bk);
                    }
                }
            }

            unsigned t0 = bk[0], t1 = bk[1], t2 = bk[2], t3 = bk[3];
            #pragma unroll
            for (int r = 0; r < 4; ++r) {
                const unsigned m = gmin8(t0);
                if (r == 0) mk0 = m; else if (r == 1) mk1 = m;
                else if (r == 2) mk2 = m; else mk3 = m;
                const bool win = (t0 == m);
                t0 = win ? t1 : t0;
                t1 = win ? t2 : t1;
                t2 = win ? t3 : t2;
                t3 = win ? ~0u : t3;
            }

            float margin = 3.0e38f;
            if (x0 > 0)     margin = fminf(margin, qx - (float)x0 * h);
            if (x1 < G - 1) margin = fminf(margin, (float)(x1 + 1) * h - qx);
            if (y0 > 0)     margin = fminf(margin, qy - (float)y0 * h);
            if (y1 < G - 1) margin = fminf(margin, (float)(y1 + 1) * h - qy);
            if (z0 > 0)     margin = fminf(margin, qz - (float)z0 * h);
            if (z1 < G - 1) margin = fminf(margin, (float)(z1 + 1) * h - qz);
            const bool covered = (margin > 1.0e37f);
            const float kd = __uint_as_float(mk3 & KMASK);   // NaN-bits if <4 found
            if (covered || (kd * 1.01f <= margin * margin)) break;  // NaN -> expand
        }

        const int nm1 = nd - 1;
        int ni_[4];
        ni_[0] = si[min((int)(mk0 & IMASK), nm1)];
        ni_[1] = si[min((int)(mk1 & IMASK), nm1)];
        ni_[2] = si[min((int)(mk2 & IMASK), nm1)];
        ni_[3] = si[min((int)(mk3 & IMASK), nm1)];

        // loss: 96-dim rows split 12 floats (3 float4) per lane in the 8-group
        const float4* q4 = (const float4*)fqp;
        const float4 qa = q4[3*sub], qb = q4[3*sub+1], qc = q4[3*sub+2];
        const float ssq = gsum8(dot4(qa,qa) + dot4(qb,qb) + dot4(qc,qc));

        float sim[4];
        #pragma unroll
        for (int k = 0; k < 4; ++k) {
            const float4* f4 = (const float4*)(fd + (size_t)ni_[k] * 96);
            const float4 da = f4[3*sub], db = f4[3*sub+1], dc = f4[3*sub+2];
            const float dotv = gsum8(dot4(qa,da) + dot4(qb,db) + dot4(qc,dc));
            const float ssd  = gsum8(dot4(da,da) + dot4(db,db) + dot4(dc,dc));
            sim[k] = dotv * rsqrtf(fmaxf(ssq, 1e-24f) * fmaxf(ssd, 1e-24f)) * 10.0f;
        }
        const float m = fmaxf(fmaxf(sim[0], sim[1]), fmaxf(sim[2], sim[3]));
        const float e0 = __expf(sim[0] - m), e1 = __expf(sim[1] - m);
        const float e2 = __expf(sim[2] - m), e3 = __expf(sim[3] - m);
        const float ssum = e0 + e1 + e2 + e3;
        const float inv = 1.0f / ssum;
        const float p2 = (e0*e0 + e1*e1 + e2*e2 + e3*e3) * inv * inv;
        if (sub == 0) acc = -__logf(p2 + 1e-12f) * scale;
    }

    acc = wave_reduce_sum(acc);
    if ((threadIdx.x & 63) == 0) atomicAdd(&partial[blockIdx.x & 63], acc);
}

__global__ __launch_bounds__(64)
void final_sum(const float* __restrict__ partial, float* __restrict__ out) {
    float v = partial[threadIdx.x];
    v = wave_reduce_sum(v);
    if (threadIdx.x == 0) out[0] = v;
}

// ============================ brute fallback ============================

#define WPB 4
template<int QPW>
__device__ __forceinline__ void brute_dir(
    const float* __restrict__ cq, const float* __restrict__ fq, int Nq,
    const float* __restrict__ cd, const float* __restrict__ fd, int Nd,
    float scale, float* __restrict__ out, int blk)
{
    const int lane = threadIdx.x & 63;
    const int widx = threadIdx.x >> 6;
    int qbase = (blk * WPB + widx) * QPW;
    if (qbase >= Nq) return;
    qbase = __builtin_amdgcn_readfirstlane(qbase);

    float qx[QPW], qy[QPW], qz[QPW];
    #pragma unroll
    for (int q = 0; q < QPW; ++q) {
        const int qi = (qbase + q < Nq) ? (qbase + q) : (Nq - 1);
        qx[q] = cq[qi*3]; qy[q] = cq[qi*3+1]; qz[q] = cq[qi*3+2];
    }
    unsigned bk[QPW][4];
    #pragma unroll
    for (int q = 0; q < QPW; ++q) {
        #pragma unroll
        for (int k = 0; k < 4; ++k) bk[q][k] = ~0u;
    }
    for (int base = 0; base < Nd; base += 64) {
        const int p = base + lane;
        const int cp = (p < Nd) ? p : (Nd - 1);
        const float px = cd[cp*3], py = cd[cp*3+1], pz = cd[cp*3+2];
        #pragma unroll
        for (int q = 0; q < QPW; ++q) {
            const float dx = px - qx[q], dy = py - qy[q], dz = pz - qz[q];
            const float d2 = dx*dx + dy*dy + dz*dz;
            unsigned k = (__float_as_uint(d2) & KMASK) | (unsigned)p;
            if (p >= Nd) k = ~0u;
            insert4u(k, bk[q]);
        }
    }
    float wacc = 0.0f;
    #pragma unroll
    for (int q = 0; q < QPW; ++q) {
        if (qbase + q >= Nq) break;
        unsigned t0 = bk[q][0], t1 = bk[q][1], t2 = bk[q][2], t3 = bk[q][3];
        int ni_[4];
        #pragma unroll
        for (int k = 0; k < 4; ++k) {
            const unsigned m = wave_min_u32(t0);
            ni_[k] = (int)(m & IMASK);
            const bool win = (t0 == m);
            t0 = win ? t1 : t0; t1 = win ? t2 : t1; t2 = win ? t3 : t2; t3 = win ? ~0u : t3;
        }
        const float* fqp = fq + (size_t)(qbase + q) * 96;
        const float qf0 = fqp[lane];
        const float qf1 = (lane < 32) ? fqp[64 + lane] : 0.0f;
        const float ssq = wave_reduce_sum(qf0*qf0 + qf1*qf1);
        float sim[4];
        #pragma unroll
        for (int k = 0; k < 4; ++k) {
            const float* fdp = fd + (size_t)ni_[k] * 96;
            const float df0 = fdp[lane];
            const float df1 = (lane < 32) ? fdp[64 + lane] : 0.0f;
            const float dotv = wave_reduce_sum(qf0*df0 + qf1*df1);
            const float ssd = wave_reduce_sum(df0*df0 + df1*df1);
            sim[k] = dotv * rsqrtf(fmaxf(ssq, 1e-24f) * fmaxf(ssd, 1e-24f)) * 10.0f;
        }
        const float m = fmaxf(fmaxf(sim[0], sim[1]), fmaxf(sim[2], sim[3]));
        const float e0 = __expf(sim[0]-m), e1 = __expf(sim[1]-m);
        const float e2 = __expf(sim[2]-m), e3 = __expf(sim[3]-m);
        const float ssum = e0+e1+e2+e3;
        const float inv = 1.0f/ssum;
        const float p2 = (e0*e0+e1*e1+e2*e2+e3*e3)*inv*inv;
        wacc += -__logf(p2 + 1e-12f);
    }
    if (lane == 0) atomicAdd(out, wacc * scale);
}

__global__ __launch_bounds__(256)
void brute_fused(const float* __restrict__ ci, const float* __restrict__ fi, int Ni,
                 const float* __restrict__ cj, const float* __restrict__ fj, int Nj,
                 float s0, float s1, int B0, int B1, float* __restrict__ out)
{
    const int bid = (int)blockIdx.x;
    const int bmin = (B0 < B1) ? B0 : B1;
    int dir, blk;
    if (bid < 2 * bmin) { dir = bid & 1; blk = bid >> 1; }
    else { dir = (B0 > B1) ? 0 : 1; blk = bid - bmin; }
    if (dir == 0) brute_dir<8>(ci, fi, Ni, cj, fj, Nj, s0, out, blk);
    else          brute_dir<4>(cj, fj, Nj, ci, fi, Ni, s1, out, blk);
}

// ============================ launch ============================

extern "C" void kernel_launch(void* const* d_in, const int* in_sizes, int n_in,
                              void* d_out, int out_size, void* d_ws, size_t ws_size,
                              hipStream_t stream) {
    const float* feat_i  = (const float*)d_in[0];
    const float* coord_i = (const float*)d_in[1];
    const float* feat_j  = (const float*)d_in[2];
    const float* coord_j = (const float*)d_in[3];
    const int Ni = in_sizes[0] / 96;
    const int Nj = in_sizes[2] / 96;
    float* out = (float*)d_out;

    auto gridfor = [](int n) {
        int g = (int)cbrtf((float)n / 4.5f);
        if (g < 2) g = 2;
        if (g > 28) g = 28;
        return g;
    };
    const int GA = gridfor(Nj), GB = gridfor(Ni);       // A: db=j, B: db=i
    const int GA3 = GA * GA * GA, GB3 = GB * GB * GB;

    size_t off = 0;
    auto alloc = [&](size_t bytes) { size_t o = off; off = (off + bytes + 15) & ~(size_t)15; return o; };
    const size_t o_soA  = alloc((size_t)Nj * 16);
    const size_t o_soB  = alloc((size_t)Ni * 16);
    const size_t o_siA  = alloc((size_t)Nj * 4);
    const size_t o_siB  = alloc((size_t)Ni * 4);
    const size_t o_stA  = alloc((size_t)(GA3 + 1) * 4);
    const size_t o_stB  = alloc((size_t)(GB3 + 1) * 4);
    const size_t o_cuA  = alloc((size_t)GA3 * 4);
    const size_t o_cuB  = alloc((size_t)GB3 * 4);
    const size_t o_part = alloc(64 * 4);

    if (ws_size >= off && Ni >= 8 && Nj >= 8 && Ni <= 32000 && Nj <= 32000) {
        char* W = (char*)d_ws;
        float4* soA = (float4*)(W + o_soA);
        float4* soB = (float4*)(W + o_soB);
        int* siA = (int*)(W + o_siA);
        int* siB = (int*)(W + o_siB);
        int* stA = (int*)(W + o_stA);
        int* stB = (int*)(W + o_stB);
        int* cuA = (int*)(W + o_cuA);
        int* cuB = (int*)(W + o_cuB);
        float* part = (float*)(W + o_part);

        const int nPts = Ni + Nj;
        const int nmax = ((GA3 > GB3) ? GA3 : GB3) + 1;

        grid_zero<<<(nmax + 255) / 256, 256, 0, stream>>>(stA, GA3 + 1, stB, GB3 + 1, part);
        grid_count<<<(nPts + 255) / 256, 256, 0, stream>>>(
            coord_j, Nj, GA, stA, coord_i, Ni, GB, stB);
        grid_scan<<<2, 256, 0, stream>>>(stA, GA3, cuA, stB, GB3, cuB);
        grid_scatter<<<(nPts + 255) / 256, 256, 0, stream>>>(
            coord_j, Nj, GA, cuA, soA, siA, coord_i, Ni, GB, cuB, soB, siB);
        knnloss<<<(nPts * 8 + 255) / 256, 256, 0, stream>>>(
            coord_i, feat_i, Ni, coord_j, feat_j, Nj,
            soA, stA, siA, GA, soB, stB, siB, GB,
            0.5f / (float)Ni, 0.5f / (float)Nj, part);
        final_sum<<<1, 64, 0, stream>>>(part, out);
    } else {
        hipMemsetAsync(out, 0, sizeof(float), stream);
        const int waves0 = (Ni + 7) / 8;
        const int B0 = (waves0 + WPB - 1) / WPB;
        const int waves1 = (Nj + 3) / 4;
        const int B1 = (waves1 + WPB - 1) / WPB;
        brute_fused<<<B0 + B1, 256, 0, stream>>>(
            coord_i, feat_i, Ni, coord_j, feat_j, Nj,
            0.5f / (float)Ni, 0.5f / (float)Nj, B0, B1, out);
    }
}